// Round 1
// baseline (1310.093 us; speedup 1.0000x reference)
//
#include <hip/hip_runtime.h>
#include <hip/hip_bf16.h>

#define DIM 256
#define MEMN 2048
#define NROWS 65536

typedef __bf16 bf16x8 __attribute__((ext_vector_type(8)));
typedef float f32x4 __attribute__((ext_vector_type(4)));

// ---------------------------------------------------------------------------
// Prep 1: memory f32 -> bf16 in two layouts:
//   mem_b [2048][256]  (row-major, for QK^T B-fragments: contiguous in d)
//   memT  [256][2048]  (transposed, for PV B-fragments: contiguous in kv)
// ---------------------------------------------------------------------------
__global__ void prep_mem_kernel(const float* __restrict__ mem,
                                __bf16* __restrict__ mem_b,
                                __bf16* __restrict__ memT) {
    __shared__ __bf16 tile[64][DIM]; // 32 KB
    int r0 = blockIdx.x * 64;
    for (int idx = threadIdx.x; idx < 64 * DIM; idx += blockDim.x) {
        int r = idx >> 8, c = idx & 255;
        float v = mem[(size_t)(r0 + r) * DIM + c];
        __bf16 b = (__bf16)v;
        mem_b[(size_t)(r0 + r) * DIM + c] = b;
        tile[r][c] = b;
    }
    __syncthreads();
    for (int idx = threadIdx.x; idx < DIM * 64; idx += blockDim.x) {
        int c = idx >> 6, r = idx & 63;
        memT[(size_t)c * MEMN + r0 + r] = tile[r][c];
    }
}

// ---------------------------------------------------------------------------
// Prep 2: mean(coords) -> 2-layer MLP -> spatial_emb[256] (fp32)
// ---------------------------------------------------------------------------
__global__ void prep_emb_kernel(const float* __restrict__ coords,
                                const float* __restrict__ w1,
                                const float* __restrict__ b1,
                                const float* __restrict__ w2,
                                const float* __restrict__ b2,
                                float* __restrict__ emb) {
    __shared__ float red[512];
    __shared__ float h[DIM];
    int t = threadIdx.x; // 256 threads
    float sx = 0.f, sy = 0.f;
    for (int i = t; i < NROWS; i += 256) {
        sx += coords[2 * i];
        sy += coords[2 * i + 1];
    }
    red[t] = sx;
    red[256 + t] = sy;
    __syncthreads();
    for (int s = 128; s > 0; s >>= 1) {
        if (t < s) {
            red[t] += red[t + s];
            red[256 + t] += red[256 + t + s];
        }
        __syncthreads();
    }
    float mx = red[0] * (1.0f / NROWS);
    float my = red[256] * (1.0f / NROWS);
    float hv = mx * w1[2 * t] + my * w1[2 * t + 1] + b1[t];
    h[t] = hv > 0.f ? hv : 0.f;
    __syncthreads();
    float acc = b2[t];
    const float* wr = w2 + (size_t)t * DIM;
    for (int k = 0; k < DIM; ++k) acc += h[k] * wr[k];
    emb[t] = acc;
}

// ---------------------------------------------------------------------------
// Main flash-attention kernel.
// Block = 256 threads = 4 waves. Each wave owns 16 query rows.
// Q (=(features+emb)/16, bf16) held in registers; loop KV tiles of 64;
// online softmax; P staged through per-wave LDS to get A-frag layout for PV.
//
// MFMA 16x16x32 bf16 layouts (verified per guide m89/m91):
//   A: row = lane&15, k = 8*(lane>>4)+i
//   B: col = lane&15, k = 8*(lane>>4)+i
//   C/D: col = lane&15, row = 4*(lane>>4)+reg
// ---------------------------------------------------------------------------
__global__ __launch_bounds__(256)
void flash_kernel(const float* __restrict__ feat,
                  const float* __restrict__ emb,
                  const __bf16* __restrict__ mem_b,
                  const __bf16* __restrict__ memT,
                  float* __restrict__ out) {
    __shared__ float s_emb[DIM];
    __shared__ __bf16 plds[4][16][64]; // per-wave P tile, 2 KB each

    int tid = threadIdx.x;
    int w = tid >> 6;
    int lane = tid & 63;
    int lr = lane & 15;  // A-row / B-col / C-col index
    int lg = lane >> 4;  // 4-lane-group id

    for (int i = tid; i < DIM; i += 256) s_emb[i] = emb[i];
    __syncthreads();

    int qbase = blockIdx.x * 64 + w * 16;

    // Load Q fragments: row = qbase+lr, d = kd*32 + lg*8 + i; scale by 1/16.
    bf16x8 qf[8];
    const float* frow = feat + (size_t)(qbase + lr) * DIM;
    #pragma unroll
    for (int kd = 0; kd < 8; ++kd) {
        int d0 = kd * 32 + lg * 8;
        const f32x4* p = reinterpret_cast<const f32x4*>(frow + d0);
        f32x4 v0 = p[0];
        f32x4 v1 = p[1];
        bf16x8 q;
        #pragma unroll
        for (int i = 0; i < 4; ++i) {
            q[i]     = (__bf16)((v0[i] + s_emb[d0 + i])     * 0.0625f);
            q[i + 4] = (__bf16)((v1[i] + s_emb[d0 + 4 + i]) * 0.0625f);
        }
        qf[kd] = q;
    }

    f32x4 o[16];
    #pragma unroll
    for (int dt = 0; dt < 16; ++dt) o[dt] = (f32x4){0.f, 0.f, 0.f, 0.f};
    float mstate[4], lstate[4];
    #pragma unroll
    for (int r = 0; r < 4; ++r) { mstate[r] = -1e30f; lstate[r] = 0.f; }

    for (int kt = 0; kt < MEMN; kt += 64) {
        // --- S = Q @ K^T (4 col-tiles of 16 kv) ---
        f32x4 s[4];
        #pragma unroll
        for (int c = 0; c < 4; ++c) s[c] = (f32x4){0.f, 0.f, 0.f, 0.f};
        #pragma unroll
        for (int kd = 0; kd < 8; ++kd) {
            int d0 = kd * 32 + lg * 8;
            #pragma unroll
            for (int c = 0; c < 4; ++c) {
                bf16x8 bk = *reinterpret_cast<const bf16x8*>(
                    mem_b + (size_t)(kt + c * 16 + lr) * DIM + d0);
                s[c] = __builtin_amdgcn_mfma_f32_16x16x32_bf16(qf[kd], bk, s[c], 0, 0, 0);
            }
        }
        // --- online softmax over these 64 cols ---
        float scale[4];
        #pragma unroll
        for (int r = 0; r < 4; ++r) {
            float pm = fmaxf(fmaxf(s[0][r], s[1][r]), fmaxf(s[2][r], s[3][r]));
            pm = fmaxf(pm, __shfl_xor(pm, 1));
            pm = fmaxf(pm, __shfl_xor(pm, 2));
            pm = fmaxf(pm, __shfl_xor(pm, 4));
            pm = fmaxf(pm, __shfl_xor(pm, 8));
            float mnew = fmaxf(mstate[r], pm);
            scale[r] = __expf(mstate[r] - mnew);
            float rs = 0.f;
            #pragma unroll
            for (int c = 0; c < 4; ++c) {
                float p = __expf(s[c][r] - mnew);
                s[c][r] = p;
                rs += p;
            }
            rs += __shfl_xor(rs, 1);
            rs += __shfl_xor(rs, 2);
            rs += __shfl_xor(rs, 4);
            rs += __shfl_xor(rs, 8);
            lstate[r] = lstate[r] * scale[r] + rs;
            mstate[r] = mnew;
        }
        // --- rescale O ---
        #pragma unroll
        for (int dt = 0; dt < 16; ++dt) {
            #pragma unroll
            for (int r = 0; r < 4; ++r) o[dt][r] *= scale[r];
        }
        // --- P -> LDS (bf16), C-layout -> A-layout transpose ---
        #pragma unroll
        for (int c = 0; c < 4; ++c) {
            #pragma unroll
            for (int r = 0; r < 4; ++r) {
                plds[w][lg * 4 + r][c * 16 + lr] = (__bf16)s[c][r];
            }
        }
        // --- O += P @ V ---
        #pragma unroll
        for (int ks = 0; ks < 2; ++ks) {
            bf16x8 pa = *reinterpret_cast<const bf16x8*>(&plds[w][lr][ks * 32 + lg * 8]);
            #pragma unroll
            for (int dt = 0; dt < 16; ++dt) {
                bf16x8 bv = *reinterpret_cast<const bf16x8*>(
                    memT + (size_t)(dt * 16 + lr) * MEMN + kt + ks * 32 + lg * 8);
                o[dt] = __builtin_amdgcn_mfma_f32_16x16x32_bf16(pa, bv, o[dt], 0, 0, 0);
            }
        }
    }

    // --- epilogue: divide by l, store ---
    #pragma unroll
    for (int r = 0; r < 4; ++r) {
        float inv = 1.f / lstate[r];
        float* orow = out + (size_t)(qbase + lg * 4 + r) * DIM;
        #pragma unroll
        for (int dt = 0; dt < 16; ++dt) {
            orow[dt * 16 + lr] = o[dt][r] * inv;
        }
    }
}

// ---------------------------------------------------------------------------
extern "C" void kernel_launch(void* const* d_in, const int* in_sizes, int n_in,
                              void* d_out, int out_size, void* d_ws, size_t ws_size,
                              hipStream_t stream) {
    const float* features = (const float*)d_in[0];
    const float* coords   = (const float*)d_in[1];
    const float* memory   = (const float*)d_in[2];
    const float* w1       = (const float*)d_in[3];
    const float* b1       = (const float*)d_in[4];
    const float* w2       = (const float*)d_in[5];
    const float* b2       = (const float*)d_in[6];
    float* out = (float*)d_out;

    // Workspace layout: emb[256] f32 (1 KB) | mem_b 1 MiB | memT 1 MiB
    float*  emb   = (float*)d_ws;
    __bf16* mem_b = (__bf16*)((char*)d_ws + 1024);
    __bf16* memT  = (__bf16*)((char*)d_ws + 1024 + (size_t)MEMN * DIM * 2);

    prep_mem_kernel<<<MEMN / 64, 256, 0, stream>>>(memory, mem_b, memT);
    prep_emb_kernel<<<1, 256, 0, stream>>>(coords, w1, b1, w2, b2, emb);
    flash_kernel<<<NROWS / 64, 256, 0, stream>>>(features, emb, mem_b, memT, out);
}

// Round 2
// 491.523 us; speedup vs baseline: 2.6654x; 2.6654x over previous
//
#include <hip/hip_runtime.h>
#include <hip/hip_bf16.h>

#define DIM 256
#define MEMN 2048
#define NROWS 65536

typedef __bf16 bf16x8 __attribute__((ext_vector_type(8)));
typedef float f32x4 __attribute__((ext_vector_type(4)));

// ---------------------------------------------------------------------------
// Prep 1: memory f32 -> bf16 in two layouts:
//   mem_b [2048][256]  (row-major; QK^T B-frags read d-contiguous)
//   memT  [256][2048]  (transposed; PV B-frags read kv-contiguous)
// ---------------------------------------------------------------------------
__global__ void prep_mem_kernel(const float* __restrict__ mem,
                                __bf16* __restrict__ mem_b,
                                __bf16* __restrict__ memT) {
    __shared__ __bf16 tile[64][DIM]; // 32 KB
    int r0 = blockIdx.x * 64;
    for (int idx = threadIdx.x; idx < 64 * DIM; idx += blockDim.x) {
        int r = idx >> 8, c = idx & 255;
        float v = mem[(size_t)(r0 + r) * DIM + c];
        __bf16 b = (__bf16)v;
        mem_b[(size_t)(r0 + r) * DIM + c] = b;
        tile[r][c] = b;
    }
    __syncthreads();
    for (int idx = threadIdx.x; idx < DIM * 64; idx += blockDim.x) {
        int c = idx >> 6, r = idx & 63;
        memT[(size_t)c * MEMN + r0 + r] = tile[r][c];
    }
}

// ---------------------------------------------------------------------------
// Prep 2: mean(coords) -> 2-layer MLP -> spatial_emb[256] (fp32)
// ---------------------------------------------------------------------------
__global__ void prep_emb_kernel(const float* __restrict__ coords,
                                const float* __restrict__ w1,
                                const float* __restrict__ b1,
                                const float* __restrict__ w2,
                                const float* __restrict__ b2,
                                float* __restrict__ emb) {
    __shared__ float red[512];
    __shared__ float h[DIM];
    int t = threadIdx.x; // 256 threads
    float sx = 0.f, sy = 0.f;
    for (int i = t; i < NROWS; i += 256) {
        sx += coords[2 * i];
        sy += coords[2 * i + 1];
    }
    red[t] = sx;
    red[256 + t] = sy;
    __syncthreads();
    for (int s = 128; s > 0; s >>= 1) {
        if (t < s) {
            red[t] += red[t + s];
            red[256 + t] += red[256 + t + s];
        }
        __syncthreads();
    }
    float mx = red[0] * (1.0f / NROWS);
    float my = red[256] * (1.0f / NROWS);
    float hv = mx * w1[2 * t] + my * w1[2 * t + 1] + b1[t];
    h[t] = hv > 0.f ? hv : 0.f;
    __syncthreads();
    float acc = b2[t];
    const float* wr = w2 + (size_t)t * DIM;
    #pragma unroll 4
    for (int k = 0; k < DIM; k += 4) {
        f32x4 wv = *reinterpret_cast<const f32x4*>(wr + k);
        acc += h[k] * wv[0] + h[k + 1] * wv[1] + h[k + 2] * wv[2] + h[k + 3] * wv[3];
    }
    emb[t] = acc;
}

// ---------------------------------------------------------------------------
// global -> LDS direct copy, 16B per lane. Dest = wave-uniform base + lane*16.
// ---------------------------------------------------------------------------
__device__ __forceinline__ void gload_lds16(const void* g, void* l) {
    __builtin_amdgcn_global_load_lds(
        (const __attribute__((address_space(1))) unsigned int*)g,
        (__attribute__((address_space(3))) unsigned int*)l,
        16, 0, 0);
}

// ---------------------------------------------------------------------------
// Flash attention. 512 threads = 8 waves, each wave 16 q rows (128/block).
// K tile [64][256] and V tile [256][64] staged in LDS per block (XOR-swizzled
// via pre-swizzled per-lane global source + linear global_load_lds dest).
//
// MFMA 16x16x32 bf16 layouts (m89/m91):
//   A: row = lane&15, k = 8*(lane>>4)+i
//   B: col = lane&15, k = 8*(lane>>4)+i
//   C/D: col = lane&15, row = 4*(lane>>4)+reg
// ---------------------------------------------------------------------------
__global__ __launch_bounds__(512, 4)
void flash_kernel(const float* __restrict__ feat,
                  const float* __restrict__ emb,
                  const __bf16* __restrict__ mem_b,
                  const __bf16* __restrict__ memT,
                  float* __restrict__ out) {
    // LDS element e of ktile holds K[kt + e/256][(e%256) ^ ((row&7)<<3)]
    __shared__ __bf16 ktile[64 * DIM];   // 32 KB
    // LDS element e of vtile holds memT[e/64][kt + ((e%64) ^ ((d&7)<<3))]
    __shared__ __bf16 vtile[DIM * 64];   // 32 KB
    __shared__ __bf16 plds[8][16 * 64];  // 16 KB (swizzled, per wave)

    const int t = threadIdx.x;
    const int w = t >> 6;
    const int lane = t & 63;
    const int lr = lane & 15;
    const int lg = lane >> 4;
    const int swz = (lr & 7) << 3;       // element-XOR for rows ≡ lr (mod 8)

    const int qbase = blockIdx.x * 128 + w * 16;

    // ---- Q fragments: row qbase+lr, d = kd*32 + lg*8 + i, scaled by 1/16 ----
    bf16x8 qf[8];
    {
        const float* frow = feat + (size_t)(qbase + lr) * DIM;
        #pragma unroll
        for (int kd = 0; kd < 8; ++kd) {
            int d0 = kd * 32 + lg * 8;
            f32x4 v0 = *reinterpret_cast<const f32x4*>(frow + d0);
            f32x4 v1 = *reinterpret_cast<const f32x4*>(frow + d0 + 4);
            f32x4 e0 = *reinterpret_cast<const f32x4*>(emb + d0);
            f32x4 e1 = *reinterpret_cast<const f32x4*>(emb + d0 + 4);
            bf16x8 q;
            #pragma unroll
            for (int i = 0; i < 4; ++i) {
                q[i]     = (__bf16)((v0[i] + e0[i]) * 0.0625f);
                q[i + 4] = (__bf16)((v1[i] + e1[i]) * 0.0625f);
            }
            qf[kd] = q;
        }
    }

    // ---- staging source patterns (invariant across kt) ----
    // K: dest elem = j*4096 + t*8  ->  row r = j*16 + (t>>5), col' = (t&31)*8
    //    src col = col' ^ ((r&7)<<3)
    const int kRow = t >> 5;                                // + j*16
    const int kCol = (((t & 31) ^ ((t >> 5) & 7))) * 8;
    // V: dest elem = j*4096 + t*8  ->  d = j*64 + (t>>3), k' = (t&7)*8
    //    src kv = k' ^ ((d&7)<<3)
    const int vD = t >> 3;                                  // + j*64
    const int vK = (((t & 7) ^ ((t >> 3) & 7))) * 8;

    f32x4 o[16];
    #pragma unroll
    for (int dt = 0; dt < 16; ++dt) o[dt] = (f32x4){0.f, 0.f, 0.f, 0.f};
    float mstate[4], lstate[4];
    #pragma unroll
    for (int r = 0; r < 4; ++r) { mstate[r] = -1e30f; lstate[r] = 0.f; }

    for (int kt = 0; kt < MEMN; kt += 64) {
        __syncthreads();  // all waves done reading previous tile
        {
            const __bf16* ksrc = mem_b + (size_t)(kt + kRow) * DIM + kCol;
            const __bf16* vsrc = memT + (size_t)vD * MEMN + kt + vK;
            char* kdst = (char*)ktile + w * 1024;
            char* vdst = (char*)vtile + w * 1024;
            #pragma unroll
            for (int j = 0; j < 4; ++j) {
                gload_lds16(ksrc + j * 16 * DIM, kdst + j * 8192);
                gload_lds16(vsrc + (size_t)j * 64 * MEMN, vdst + j * 8192);
            }
        }
        asm volatile("s_waitcnt vmcnt(0)" ::: "memory");
        __syncthreads();  // tiles visible to all waves

        // ---- S = Q @ K^T : 4 col-tiles of 16 kv ----
        f32x4 s[4];
        #pragma unroll
        for (int c = 0; c < 4; ++c) s[c] = (f32x4){0.f, 0.f, 0.f, 0.f};
        #pragma unroll
        for (int kd = 0; kd < 8; ++kd) {
            int d0 = kd * 32 + lg * 8;
            #pragma unroll
            for (int c = 0; c < 4; ++c) {
                int row = c * 16 + lr;
                const bf16x8 bk = *reinterpret_cast<const bf16x8*>(
                    ktile + row * DIM + (d0 ^ swz));
                s[c] = __builtin_amdgcn_mfma_f32_16x16x32_bf16(qf[kd], bk, s[c], 0, 0, 0);
            }
        }

        // ---- online softmax (rows q = lg*4 + r; reduce over lane&15) ----
        float scale[4];
        #pragma unroll
        for (int r = 0; r < 4; ++r) {
            float pm = fmaxf(fmaxf(s[0][r], s[1][r]), fmaxf(s[2][r], s[3][r]));
            pm = fmaxf(pm, __shfl_xor(pm, 1));
            pm = fmaxf(pm, __shfl_xor(pm, 2));
            pm = fmaxf(pm, __shfl_xor(pm, 4));
            pm = fmaxf(pm, __shfl_xor(pm, 8));
            float mnew = fmaxf(mstate[r], pm);
            scale[r] = __expf(mstate[r] - mnew);
            float rs = 0.f;
            #pragma unroll
            for (int c = 0; c < 4; ++c) {
                float p = __expf(s[c][r] - mnew);
                s[c][r] = p;
                rs += p;
            }
            rs += __shfl_xor(rs, 1);
            rs += __shfl_xor(rs, 2);
            rs += __shfl_xor(rs, 4);
            rs += __shfl_xor(rs, 8);
            lstate[r] = lstate[r] * scale[r] + rs;
            mstate[r] = mnew;
        }
        // ---- rescale O ----
        #pragma unroll
        for (int dt = 0; dt < 16; ++dt) {
            #pragma unroll
            for (int r = 0; r < 4; ++r) o[dt][r] *= scale[r];
        }
        // ---- P -> per-wave LDS (swizzled), C-layout -> A-layout ----
        #pragma unroll
        for (int c = 0; c < 4; ++c) {
            #pragma unroll
            for (int r = 0; r < 4; ++r) {
                int row = lg * 4 + r;
                plds[w][row * 64 + ((c * 16 + lr) ^ ((row & 7) << 3))] = (__bf16)s[c][r];
            }
        }
        // ---- O += P @ V ----
        #pragma unroll
        for (int ks = 0; ks < 2; ++ks) {
            int k0 = ks * 32 + lg * 8;
            const bf16x8 pa = *reinterpret_cast<const bf16x8*>(
                &plds[w][lr * 64 + (k0 ^ swz)]);
            #pragma unroll
            for (int dt = 0; dt < 16; ++dt) {
                int d = dt * 16 + lr;
                const bf16x8 bv = *reinterpret_cast<const bf16x8*>(
                    vtile + d * 64 + (k0 ^ swz));
                o[dt] = __builtin_amdgcn_mfma_f32_16x16x32_bf16(pa, bv, o[dt], 0, 0, 0);
            }
        }
    }

    // ---- epilogue ----
    #pragma unroll
    for (int r = 0; r < 4; ++r) {
        float inv = 1.f / lstate[r];
        float* orow = out + (size_t)(qbase + lg * 4 + r) * DIM;
        #pragma unroll
        for (int dt = 0; dt < 16; ++dt) {
            orow[dt * 16 + lr] = o[dt][r] * inv;
        }
    }
}

// ---------------------------------------------------------------------------
extern "C" void kernel_launch(void* const* d_in, const int* in_sizes, int n_in,
                              void* d_out, int out_size, void* d_ws, size_t ws_size,
                              hipStream_t stream) {
    const float* features = (const float*)d_in[0];
    const float* coords   = (const float*)d_in[1];
    const float* memory   = (const float*)d_in[2];
    const float* w1       = (const float*)d_in[3];
    const float* b1       = (const float*)d_in[4];
    const float* w2       = (const float*)d_in[5];
    const float* b2       = (const float*)d_in[6];
    float* out = (float*)d_out;

    // Workspace: emb[256] f32 (1 KB) | mem_b 1 MiB | memT 1 MiB
    float*  emb   = (float*)d_ws;
    __bf16* mem_b = (__bf16*)((char*)d_ws + 1024);
    __bf16* memT  = (__bf16*)((char*)d_ws + 1024 + (size_t)MEMN * DIM * 2);

    prep_mem_kernel<<<MEMN / 64, 256, 0, stream>>>(memory, mem_b, memT);
    prep_emb_kernel<<<1, 256, 0, stream>>>(coords, w1, b1, w2, b2, emb);
    flash_kernel<<<NROWS / 128, 512, 0, stream>>>(features, emb, mem_b, memT, out);
}

// Round 3
// 269.951 us; speedup vs baseline: 4.8531x; 1.8208x over previous
//
#include <hip/hip_runtime.h>
#include <hip/hip_bf16.h>

#define DIM 256
#define MEMN 2048
#define NROWS 65536
#define NT 32   // kv tiles of 64

typedef __bf16 bf16x8 __attribute__((ext_vector_type(8)));
typedef float f32x4 __attribute__((ext_vector_type(4)));
typedef float f32x16 __attribute__((ext_vector_type(16)));
typedef unsigned int uint32x4 __attribute__((ext_vector_type(4)));

// ---------------------------------------------------------------------------
// Prep: memory f32 -> packed per-tile blob, pre-swizzled for LDS reads.
// Tile t (64 KB = 32768 bf16):
//   K-part elems [0,16384): (kv,x): holds K[kt+kv][ x ^ ((kv&31)<<3) ]
//   V-part elems [16384,32768): (R,x) R=row of 128 elems:
//       L = x ^ ((R&15)<<3); holds V^T[d=2R+(L>>6)][kv=L&63] = mem[kt+kv][d]
// ---------------------------------------------------------------------------
__global__ void prep_blob_kernel(const float* __restrict__ mem,
                                 __bf16* __restrict__ blob) {
    int tile = blockIdx.x;
    int kt = tile * 64;
    __bf16* kb = blob + (size_t)tile * 32768;
    __bf16* vb = kb + 16384;
    for (int e = threadIdx.x; e < 16384; e += blockDim.x) {
        int kv = e >> 8, x = e & 255;
        int dd = x ^ ((kv & 31) << 3);
        kb[e] = (__bf16)mem[(size_t)(kt + kv) * DIM + dd];
        int R = e >> 7, j = e & 127;
        int jp = j ^ ((R & 15) << 3);
        int d = 2 * R + (jp >> 6), kv2 = jp & 63;
        vb[e] = (__bf16)mem[(size_t)(kt + kv2) * DIM + d];
    }
}

// ---------------------------------------------------------------------------
// Prep 2: mean(coords) -> 2-layer MLP -> spatial_emb[256] (fp32)
// ---------------------------------------------------------------------------
__global__ void prep_emb_kernel(const float* __restrict__ coords,
                                const float* __restrict__ w1,
                                const float* __restrict__ b1,
                                const float* __restrict__ w2,
                                const float* __restrict__ b2,
                                float* __restrict__ emb) {
    __shared__ float red[512];
    __shared__ float h[DIM];
    int t = threadIdx.x; // 256 threads
    float sx = 0.f, sy = 0.f;
    for (int i = t; i < NROWS; i += 256) {
        sx += coords[2 * i];
        sy += coords[2 * i + 1];
    }
    red[t] = sx;
    red[256 + t] = sy;
    __syncthreads();
    for (int s = 128; s > 0; s >>= 1) {
        if (t < s) {
            red[t] += red[t + s];
            red[256 + t] += red[256 + t + s];
        }
        __syncthreads();
    }
    float mx = red[0] * (1.0f / NROWS);
    float my = red[256] * (1.0f / NROWS);
    float hv = mx * w1[2 * t] + my * w1[2 * t + 1] + b1[t];
    h[t] = hv > 0.f ? hv : 0.f;
    __syncthreads();
    float acc = b2[t];
    const float* wr = w2 + (size_t)t * DIM;
    #pragma unroll 4
    for (int k = 0; k < DIM; k += 4) {
        f32x4 wv = *reinterpret_cast<const f32x4*>(wr + k);
        acc += h[k] * wv[0] + h[k + 1] * wv[1] + h[k + 2] * wv[2] + h[k + 3] * wv[3];
    }
    emb[t] = acc;
}

// ---------------------------------------------------------------------------
__device__ __forceinline__ void gload_lds16(const void* g, void* l) {
    __builtin_amdgcn_global_load_lds(
        (const __attribute__((address_space(1))) unsigned int*)g,
        (__attribute__((address_space(3))) unsigned int*)l,
        16, 0, 0);
}

__device__ __forceinline__ unsigned int pkbf(float a, float b) {
    union { __bf16 h; unsigned short u; } ua, ub;
    ua.h = (__bf16)a; ub.h = (__bf16)b;
    return (unsigned int)ua.u | ((unsigned int)ub.u << 16);
}

// ---------------------------------------------------------------------------
// Flash attention, swapped-operand 32x32x16 form.
// 512 threads = 8 waves; each wave owns 32 q rows; block = 256 q; grid = 256.
//
// 32x32x16 bf16 layouts (guide §3, m74/m101 C/D verified):
//   A: row = lane&31, k = 8*(lane>>5)+i
//   B: col = lane&31, k = 8*(lane>>5)+i
//   C/D: col = lane&31, row = (reg&3) + 8*(reg>>2) + 4*(lane>>5)
//
// QK^T (swapped): S^T[kv][q] = mfma(A=K, B=Q)  -> lane holds 32 scores for
//   its own q = lane&31 (kv rows split across hi halves).
// Softmax: in-lane over 32 + one shfl_xor(32). Defer-max THR=8 (T13).
// PV (swapped): O^T[d][q] = mfma(A=V^T, B=P^T); P^T B-frags built in-register
//   via packed-bf16 word exchange with the hi/lo partner lane (T12 pattern).
// ---------------------------------------------------------------------------
__global__ __launch_bounds__(512, 2)
void flash_kernel(const float* __restrict__ feat,
                  const float* __restrict__ emb,
                  const __bf16* __restrict__ blob,
                  float* __restrict__ out) {
    __shared__ __bf16 lds[2][32768]; // 2 x 64 KB double buffer

    const int t = threadIdx.x;
    const int w = t >> 6;
    const int lane = t & 63;
    const int ln = lane & 31;
    const int hi = lane >> 5;

    const int qrow = blockIdx.x * 256 + w * 32 + ln;

    // ---- Q B-frags: B[k=d][n=q]: lane holds Q[qrow][kd*16 + 8*hi + i] ----
    bf16x8 qf[16];
    {
        const float* frow = feat + (size_t)qrow * DIM;
        #pragma unroll
        for (int kd = 0; kd < 16; ++kd) {
            int d0 = kd * 16 + hi * 8;
            f32x4 a = *reinterpret_cast<const f32x4*>(frow + d0);
            f32x4 b = *reinterpret_cast<const f32x4*>(frow + d0 + 4);
            f32x4 ea = *reinterpret_cast<const f32x4*>(emb + d0);
            f32x4 eb = *reinterpret_cast<const f32x4*>(emb + d0 + 4);
            bf16x8 q;
            #pragma unroll
            for (int i = 0; i < 4; ++i) {
                q[i]     = (__bf16)((a[i] + ea[i]) * 0.0625f);
                q[i + 4] = (__bf16)((b[i] + eb[i]) * 0.0625f);
            }
            qf[kd] = q;
        }
    }

    f32x16 o[8];
    #pragma unroll
    for (int dt = 0; dt < 8; ++dt) o[dt] = (f32x16)(0.f);
    float m = -1e30f, l = 0.f;

    // lane-invariant LDS byte offsets
    const int k_eoff0 = ((hi * 8) ^ (ln * 8)) * 2;        // + kd*32 xor-consistent
    const int v_row = (ln >> 1);                          // + dt*16
    // staging addresses
    const char* gbase = (const char*)blob + (size_t)w * 8192 + (size_t)lane * 16;
    char* lbase0 = (char*)&lds[0][0] + w * 8192;
    char* lbase1 = (char*)&lds[1][0] + w * 8192;

    // prologue: stage tile 0 into buf 0
    #pragma unroll
    for (int j = 0; j < 8; ++j)
        gload_lds16(gbase + j * 1024, lbase0 + j * 1024);

    #pragma unroll 1
    for (int kt = 0; kt < NT; ++kt) {
        const int cur = kt & 1;
        if (kt + 1 < NT) {
            const char* g = gbase + (size_t)(kt + 1) * 65536;
            char* lb = cur ? lbase0 : lbase1;
            #pragma unroll
            for (int j = 0; j < 8; ++j)
                gload_lds16(g + j * 1024, lb + j * 1024);
            asm volatile("s_waitcnt vmcnt(8)" ::: "memory");
        } else {
            asm volatile("s_waitcnt vmcnt(0)" ::: "memory");
        }
        __builtin_amdgcn_s_barrier();
        asm volatile("" ::: "memory");

        const char* buf = (const char*)&lds[cur][0];

        // ---- QK^T: S^T = mfma(K, Q), two 32-kv tiles ----
        f32x16 s[2];
        s[0] = (f32x16)(0.f);
        s[1] = (f32x16)(0.f);
        #pragma unroll
        for (int kd = 0; kd < 16; ++kd) {
            int eoff = (((kd * 16 + hi * 8) ^ (ln * 8)) << 1);
            bf16x8 a0 = *reinterpret_cast<const bf16x8*>(buf + ln * 512 + eoff);
            bf16x8 a1 = *reinterpret_cast<const bf16x8*>(buf + (32 + ln) * 512 + eoff);
            s[0] = __builtin_amdgcn_mfma_f32_32x32x16_bf16(a0, qf[kd], s[0], 0, 0, 0);
            s[1] = __builtin_amdgcn_mfma_f32_32x32x16_bf16(a1, qf[kd], s[1], 0, 0, 0);
        }

        // ---- softmax (q = ln, lane-local; combine hi halves) ----
        float pmax = -1e30f;
        #pragma unroll
        for (int e = 0; e < 16; ++e) {
            pmax = fmaxf(pmax, s[0][e]);
            pmax = fmaxf(pmax, s[1][e]);
        }
        pmax = fmaxf(pmax, __shfl_xor(pmax, 32));
        if (pmax > m + 8.f) {   // defer-max (T13)
            float sc = __expf(m - pmax);
            m = pmax;
            l *= sc;
            #pragma unroll
            for (int dt = 0; dt < 8; ++dt) o[dt] *= sc;
        }
        float ladd = 0.f;
        #pragma unroll
        for (int e = 0; e < 16; ++e) {
            float p0 = __expf(s[0][e] - m);
            float p1 = __expf(s[1][e] - m);
            s[0][e] = p0;
            s[1][e] = p1;
            ladd += p0 + p1;
        }
        ladd += __shfl_xor(ladd, 32);
        l += ladd;

        // ---- PV: O^T += mfma(V^T, P^T) over 4 k-steps of 16 kv ----
        #pragma unroll
        for (int ks = 0; ks < 4; ++ks) {
            const int c = ks >> 1;
            const int b = 8 * (ks & 1);
            // packed words for gl = 2*(ks&1) (even) and +1 (odd)
            unsigned int we0 = pkbf(s[c][b + 0], s[c][b + 1]);
            unsigned int we1 = pkbf(s[c][b + 2], s[c][b + 3]);
            unsigned int wo0 = pkbf(s[c][b + 4], s[c][b + 5]);
            unsigned int wo1 = pkbf(s[c][b + 6], s[c][b + 7]);
            unsigned int send0 = hi ? we0 : wo0;
            unsigned int send1 = hi ? we1 : wo1;
            unsigned int r0 = __shfl_xor(send0, 32);
            unsigned int r1 = __shfl_xor(send1, 32);
            unsigned int own0 = hi ? wo0 : we0;
            unsigned int own1 = hi ? wo1 : we1;
            uint32x4 fw;
            fw[0] = hi ? r0 : own0;
            fw[1] = hi ? r1 : own1;
            fw[2] = hi ? own0 : r0;
            fw[3] = hi ? own1 : r1;
            bf16x8 pb = __builtin_bit_cast(bf16x8, fw);

            int ebase = ((((ln & 1) * 64 + ks * 16 + hi * 8) ^ ((ln >> 1) * 8)) << 1);
            #pragma unroll
            for (int dt = 0; dt < 8; ++dt) {
                int row = dt * 16 + v_row;
                bf16x8 va = *reinterpret_cast<const bf16x8*>(
                    buf + 32768 + row * 256 + ebase);
                o[dt] = __builtin_amdgcn_mfma_f32_32x32x16_bf16(va, pb, o[dt], 0, 0, 0);
            }
        }

        asm volatile("" ::: "memory");
        __builtin_amdgcn_s_barrier();
        asm volatile("" ::: "memory");
    }

    // ---- epilogue: lane-local l; 16B stores of 4 consecutive d ----
    float linv = 1.f / l;
    float* orow = out + (size_t)qrow * DIM;
    #pragma unroll
    for (int dt = 0; dt < 8; ++dt) {
        #pragma unroll
        for (int rg = 0; rg < 4; ++rg) {
            f32x4 v;
            v[0] = o[dt][4 * rg + 0] * linv;
            v[1] = o[dt][4 * rg + 1] * linv;
            v[2] = o[dt][4 * rg + 2] * linv;
            v[3] = o[dt][4 * rg + 3] * linv;
            *reinterpret_cast<f32x4*>(orow + dt * 32 + 8 * rg + 4 * hi) = v;
        }
    }
}

// ---------------------------------------------------------------------------
extern "C" void kernel_launch(void* const* d_in, const int* in_sizes, int n_in,
                              void* d_out, int out_size, void* d_ws, size_t ws_size,
                              hipStream_t stream) {
    const float* features = (const float*)d_in[0];
    const float* coords   = (const float*)d_in[1];
    const float* memory   = (const float*)d_in[2];
    const float* w1       = (const float*)d_in[3];
    const float* b1       = (const float*)d_in[4];
    const float* w2       = (const float*)d_in[5];
    const float* b2       = (const float*)d_in[6];
    float* out = (float*)d_out;

    // Workspace: emb[256] f32 (1 KB) | blob 2 MiB
    float*  emb  = (float*)d_ws;
    __bf16* blob = (__bf16*)((char*)d_ws + 1024);

    prep_blob_kernel<<<NT, 256, 0, stream>>>(memory, blob);
    prep_emb_kernel<<<1, 256, 0, stream>>>(coords, w1, b1, w2, b2, emb);
    flash_kernel<<<NROWS / 256, 512, 0, stream>>>(features, emb, blob, out);
}

// Round 4
// 240.477 us; speedup vs baseline: 5.4479x; 1.1226x over previous
//
#include <hip/hip_runtime.h>
#include <hip/hip_bf16.h>

#define DIM 256
#define MEMN 2048
#define NROWS 65536
#define KVB 32
#define NT 64            // MEMN / KVB
#define TILE_B 32768     // bytes per blob tile (K 16KB + V 16KB)

typedef __bf16 bf16x8 __attribute__((ext_vector_type(8)));
typedef float f32x4 __attribute__((ext_vector_type(4)));
typedef float f32x16 __attribute__((ext_vector_type(16)));
typedef unsigned int uint32x4 __attribute__((ext_vector_type(4)));

// ---------------------------------------------------------------------------
// Prep A: coords partial sums. 64 blocks x 256 threads, fully coalesced.
// partial[0..63] = sum x per block, partial[64..127] = sum y per block.
// ---------------------------------------------------------------------------
__global__ void prep_coords_kernel(const float* __restrict__ coords,
                                   float* __restrict__ partial) {
    __shared__ float red[512];
    int b = blockIdx.x, t = threadIdx.x;
    const f32x4* src = reinterpret_cast<const f32x4*>(coords + (size_t)b * 2048);
    f32x4 v0 = src[t * 2];
    f32x4 v1 = src[t * 2 + 1];
    red[t]       = v0[0] + v0[2] + v1[0] + v1[2];
    red[256 + t] = v0[1] + v0[3] + v1[1] + v1[3];
    __syncthreads();
    for (int s = 128; s > 0; s >>= 1) {
        if (t < s) { red[t] += red[t + s]; red[256 + t] += red[256 + t + s]; }
        __syncthreads();
    }
    if (t == 0) { partial[b] = red[0]; partial[64 + b] = red[256]; }
}

// ---------------------------------------------------------------------------
// Prep B: reduce partials -> mean -> 2-layer MLP -> spatial_emb[256]
// ---------------------------------------------------------------------------
__global__ void prep_emb_kernel(const float* __restrict__ partial,
                                const float* __restrict__ w1,
                                const float* __restrict__ b1,
                                const float* __restrict__ w2,
                                const float* __restrict__ b2,
                                float* __restrict__ emb) {
    __shared__ float red[128];
    __shared__ float h[DIM];
    int t = threadIdx.x; // 256
    if (t < 128) red[t] = partial[t];
    __syncthreads();
    for (int s = 32; s > 0; s >>= 1) {
        if (t < s) { red[t] += red[t + s]; red[64 + t] += red[64 + t + s]; }
        __syncthreads();
    }
    float mx = red[0] * (1.0f / NROWS);
    float my = red[64] * (1.0f / NROWS);
    float hv = mx * w1[2 * t] + my * w1[2 * t + 1] + b1[t];
    h[t] = hv > 0.f ? hv : 0.f;
    __syncthreads();
    float acc = b2[t];
    const float* wr = w2 + (size_t)t * DIM;
    #pragma unroll 4
    for (int k = 0; k < DIM; k += 4) {
        f32x4 wv = *reinterpret_cast<const f32x4*>(wr + k);
        acc += h[k] * wv[0] + h[k + 1] * wv[1] + h[k + 2] * wv[2] + h[k + 3] * wv[3];
    }
    emb[t] = acc;
}

// ---------------------------------------------------------------------------
// Prep C: memory f32 -> packed per-tile blob (KVB=32), pre-swizzled.
// Tile t (32768 B):
//   K part elems [0,8192): (kv 0..31, x 0..255) holds K[kt+kv][x ^ (kv<<3)]
//   V part elems [8192,16384): rows R 0..63 of 128 elems:
//       L = j ^ ((R&15)<<3); holds V^T[d=4R+(L>>5)][kv=L&31] = mem[kt+kv][d]
// ---------------------------------------------------------------------------
__global__ void prep_blob_kernel(const float* __restrict__ mem,
                                 __bf16* __restrict__ blob) {
    __shared__ __bf16 ltile[KVB][DIM]; // 16 KB
    int tile = blockIdx.x, t = threadIdx.x;
    int kt = tile * KVB;
    // coalesced load 32x256 f32 -> bf16 LDS
    for (int c = t; c < 1024; c += 256) {
        int e = c * 8, row = e >> 8, col = e & 255;
        const float* s = mem + (size_t)(kt + row) * DIM + col;
        f32x4 a = *reinterpret_cast<const f32x4*>(s);
        f32x4 b = *reinterpret_cast<const f32x4*>(s + 4);
        bf16x8 o;
        #pragma unroll
        for (int j = 0; j < 4; ++j) { o[j] = (__bf16)a[j]; o[j + 4] = (__bf16)b[j]; }
        *reinterpret_cast<bf16x8*>(&ltile[row][col]) = o;
    }
    __syncthreads();
    __bf16* kb = blob + (size_t)tile * 16384;
    __bf16* vb = kb + 8192;
    for (int c = t; c < 1024; c += 256) {
        int e = c * 8, kv = e >> 8, x0 = e & 255;
        bf16x8 o = *reinterpret_cast<const bf16x8*>(&ltile[kv][x0 ^ (kv << 3)]);
        *reinterpret_cast<bf16x8*>(kb + e) = o;
    }
    for (int c = t; c < 1024; c += 256) {
        int idx = c * 8, R = idx >> 7, j0 = idx & 127;
        int L0 = j0 ^ ((R & 15) << 3);
        int d = 4 * R + (L0 >> 5), kv0 = L0 & 31;
        bf16x8 o;
        #pragma unroll
        for (int j = 0; j < 8; ++j) o[j] = ltile[kv0 + j][d];
        *reinterpret_cast<bf16x8*>(vb + idx) = o;
    }
}

// ---------------------------------------------------------------------------
__device__ __forceinline__ void gload_lds16(const void* g, void* l) {
    __builtin_amdgcn_global_load_lds(
        (const __attribute__((address_space(1))) unsigned int*)g,
        (__attribute__((address_space(3))) unsigned int*)l,
        16, 0, 0);
}

__device__ __forceinline__ unsigned int pkbf(float a, float b) {
    union { __bf16 h; unsigned short u; } ua, ub;
    ua.h = (__bf16)a; ub.h = (__bf16)b;
    return (unsigned int)ua.u | ((unsigned int)ub.u << 16);
}

// ---------------------------------------------------------------------------
// Flash attention, lag-1 pipelined: per iter {QKT(t+1) | softmax(t) | PV(t)}.
// 512 thr = 8 waves x 32 q rows; KVB=32; 3 LDS buffers, stage leads by 2,
// counted vmcnt(4), raw s_barrier (no vmcnt(0) drain in main loop).
//
// 32x32x16 bf16 layouts (m74/m101):
//   A: row = lane&31, k = 8*(lane>>5)+i
//   B: col = lane&31, k = 8*(lane>>5)+i
//   C/D: col = lane&31, row = (reg&3) + 8*(reg>>2) + 4*(lane>>5)
// ---------------------------------------------------------------------------
__global__ __launch_bounds__(512, 2)
void flash_kernel(const float* __restrict__ feat,
                  const float* __restrict__ emb,
                  const __bf16* __restrict__ blob,
                  float* __restrict__ out) {
    __shared__ char smem[3 * TILE_B]; // 96 KB

    const int t = threadIdx.x;
    const int w = t >> 6;
    const int lane = t & 63;
    const int ln = lane & 31;
    const int hi = lane >> 5;

    const int qrow = blockIdx.x * 256 + w * 32 + ln;

    // ---- Q B-frags ----
    bf16x8 qf[16];
    {
        const float* frow = feat + (size_t)qrow * DIM;
        #pragma unroll
        for (int kd = 0; kd < 16; ++kd) {
            int d0 = kd * 16 + hi * 8;
            f32x4 a = *reinterpret_cast<const f32x4*>(frow + d0);
            f32x4 b = *reinterpret_cast<const f32x4*>(frow + d0 + 4);
            f32x4 ea = *reinterpret_cast<const f32x4*>(emb + d0);
            f32x4 eb = *reinterpret_cast<const f32x4*>(emb + d0 + 4);
            bf16x8 q;
            #pragma unroll
            for (int i = 0; i < 4; ++i) {
                q[i]     = (__bf16)((a[i] + ea[i]) * 0.0625f);
                q[i + 4] = (__bf16)((b[i] + eb[i]) * 0.0625f);
            }
            qf[kd] = q;
        }
    }

    f32x16 o[8];
    #pragma unroll
    for (int dt = 0; dt < 8; ++dt) o[dt] = (f32x16)(0.f);
    float m = -1e30f, l = 0.f;

    // staging addresses: per-wave 4 KB slice of each 32 KB tile
    const char* gsl = (const char*)blob + w * 1024 + lane * 16;
    char* bA = smem;               // tile t
    char* bB = smem + TILE_B;      // tile t+1
    char* bC = smem + 2 * TILE_B;  // staging target t+2

    #define STAGE(k, buf)                                            \
        {   const char* _g = gsl + (size_t)(k) * TILE_B;             \
            char* _d = (buf) + w * 1024;                             \
            _Pragma("unroll")                                        \
            for (int _j = 0; _j < 4; ++_j)                           \
                gload_lds16(_g + _j * 8192, _d + _j * 8192);         \
        }

    #define QKT(buf, dst)                                                        \
        {   f32x16 _acc = (f32x16)(0.f);                                         \
            const char* _kb = (buf) + ln * 512;                                  \
            __builtin_amdgcn_s_setprio(1);                                       \
            _Pragma("unroll")                                                    \
            for (int _kd = 0; _kd < 16; ++_kd) {                                 \
                const bf16x8 _a = *reinterpret_cast<const bf16x8*>(              \
                    _kb + (((_kd * 16 + hi * 8) ^ (ln * 8)) << 1));              \
                _acc = __builtin_amdgcn_mfma_f32_32x32x16_bf16(_a, qf[_kd], _acc, 0, 0, 0); \
            }                                                                    \
            __builtin_amdgcn_s_setprio(0);                                       \
            (dst) = _acc;                                                        \
        }

    // prologue
    STAGE(0, bA);
    STAGE(1, bB);
    asm volatile("s_waitcnt vmcnt(4)" ::: "memory");
    __builtin_amdgcn_s_barrier();
    asm volatile("" ::: "memory");
    f32x16 s_cur, s_nxt;
    QKT(bA, s_cur);

    #pragma unroll 1
    for (int kt = 0; kt < NT; ++kt) {
        if (kt + 2 < NT) STAGE(kt + 2, bC);
        if (kt + 1 < NT) {
            if (kt + 2 < NT) {
                asm volatile("s_waitcnt vmcnt(4)" ::: "memory");
            } else {
                asm volatile("s_waitcnt vmcnt(0)" ::: "memory");
            }
            __builtin_amdgcn_s_barrier();
            asm volatile("" ::: "memory");
            QKT(bB, s_nxt);
        }

        // ---- softmax(kt) on s_cur (q = ln; combine hi halves) ----
        float pmax = -1e30f;
        #pragma unroll
        for (int e = 0; e < 16; ++e) pmax = fmaxf(pmax, s_cur[e]);
        pmax = fmaxf(pmax, __shfl_xor(pmax, 32));
        if (pmax > m + 8.f) {   // defer-max (T13)
            float sc = __expf(m - pmax);
            m = pmax;
            l *= sc;
            #pragma unroll
            for (int dt = 0; dt < 8; ++dt) o[dt] = o[dt] * sc;
        }
        f32x16 p;
        float ladd = 0.f;
        #pragma unroll
        for (int e = 0; e < 16; ++e) {
            float pe = __expf(s_cur[e] - m);
            p[e] = pe;
            ladd += pe;
        }
        ladd += __shfl_xor(ladd, 32);
        l += ladd;

        // ---- PV(kt): O^T += mfma(V^T, P^T), 2 k-steps of 16 kv ----
        #pragma unroll
        for (int ks = 0; ks < 2; ++ks) {
            unsigned w01 = pkbf(p[ks * 8 + 0], p[ks * 8 + 1]);
            unsigned w23 = pkbf(p[ks * 8 + 2], p[ks * 8 + 3]);
            unsigned w45 = pkbf(p[ks * 8 + 4], p[ks * 8 + 5]);
            unsigned w67 = pkbf(p[ks * 8 + 6], p[ks * 8 + 7]);
            unsigned sA = hi ? w01 : w45;
            unsigned sB = hi ? w23 : w67;
            unsigned oA = hi ? w45 : w01;
            unsigned oB = hi ? w67 : w23;
            unsigned rA = __shfl_xor(sA, 32);
            unsigned rB = __shfl_xor(sB, 32);
            uint32x4 fw;
            fw[0] = hi ? rA : oA;
            fw[1] = hi ? rB : oB;
            fw[2] = hi ? oA : rA;
            fw[3] = hi ? oB : rB;
            bf16x8 pb = __builtin_bit_cast(bf16x8, fw);
            const int kv0 = ks * 16 + hi * 8;
            __builtin_amdgcn_s_setprio(1);
            #pragma unroll
            for (int dt = 0; dt < 8; ++dt) {
                int R = dt * 8 + (ln >> 2);
                int j = (((ln & 3) * 32 + kv0) ^ ((R & 15) << 3));
                const bf16x8 va = *reinterpret_cast<const bf16x8*>(
                    bA + 16384 + R * 256 + 2 * j);
                o[dt] = __builtin_amdgcn_mfma_f32_32x32x16_bf16(va, pb, o[dt], 0, 0, 0);
            }
            __builtin_amdgcn_s_setprio(0);
        }

        asm volatile("s_waitcnt lgkmcnt(0)" ::: "memory");
        __builtin_amdgcn_s_barrier();
        asm volatile("" ::: "memory");

        // rotate buffers, advance score pipeline
        char* tmp = bA; bA = bB; bB = bC; bC = tmp;
        s_cur = s_nxt;
    }

    // ---- epilogue: coalesced stores via LDS, 4 phases of 2 waves ----
    float linv = 1.f / l;
    const char* outb = (const char*)out;
    #pragma unroll 1
    for (int ph = 0; ph < 4; ++ph) {
        if ((w >> 1) == ph) {
            char* base = smem + (w & 1) * 32768 + ln * 1024;
            const int sw = (ln & 7) << 4;
            #pragma unroll
            for (int dt = 0; dt < 8; ++dt) {
                #pragma unroll
                for (int g = 0; g < 4; ++g) {
                    f32x4 v;
                    v[0] = o[dt][4 * g + 0] * linv;
                    v[1] = o[dt][4 * g + 1] * linv;
                    v[2] = o[dt][4 * g + 2] * linv;
                    v[3] = o[dt][4 * g + 3] * linv;
                    *reinterpret_cast<f32x4*>(base + ((dt * 128 + g * 32 + hi * 16) ^ sw)) = v;
                }
            }
        }
        __syncthreads();
        {
            char* gdst = (char*)out + ((size_t)blockIdx.x * 256 + ph * 64) * 1024;
            #pragma unroll
            for (int i = 0; i < 8; ++i) {
                int bo = t * 16 + i * 8192;
                int r = bo >> 10, off = bo & 1023;
                f32x4 v = *reinterpret_cast<const f32x4*>(
                    smem + r * 1024 + (off ^ ((r & 7) << 4)));
                *reinterpret_cast<f32x4*>(gdst + (size_t)r * 1024 + off) = v;
            }
        }
        __syncthreads();
    }
    #undef STAGE
    #undef QKT
}

// ---------------------------------------------------------------------------
extern "C" void kernel_launch(void* const* d_in, const int* in_sizes, int n_in,
                              void* d_out, int out_size, void* d_ws, size_t ws_size,
                              hipStream_t stream) {
    const float* features = (const float*)d_in[0];
    const float* coords   = (const float*)d_in[1];
    const float* memory   = (const float*)d_in[2];
    const float* w1       = (const float*)d_in[3];
    const float* b1       = (const float*)d_in[4];
    const float* w2       = (const float*)d_in[5];
    const float* b2       = (const float*)d_in[6];
    float* out = (float*)d_out;

    // ws: partial[128]f @0 | emb[256]f @512B | blob 2MiB @2048B
    float*  partial = (float*)d_ws;
    float*  emb     = (float*)((char*)d_ws + 512);
    __bf16* blob    = (__bf16*)((char*)d_ws + 2048);

    prep_coords_kernel<<<64, 256, 0, stream>>>(coords, partial);
    prep_blob_kernel<<<NT, 256, 0, stream>>>(memory, blob);
    prep_emb_kernel<<<1, 256, 0, stream>>>(partial, w1, b1, w2, b2, emb);
    flash_kernel<<<NROWS / 256, 512, 0, stream>>>(features, emb, blob, out);
}

// Round 5
// 240.267 us; speedup vs baseline: 5.4526x; 1.0009x over previous
//
#include <hip/hip_runtime.h>
#include <hip/hip_bf16.h>

#define DIM 256
#define MEMN 2048
#define NROWS 65536
#define KVB 32
#define NT 64            // MEMN / KVB
#define TILE_B 32768     // bytes per blob tile (K 16KB + V 16KB)

typedef __bf16 bf16x8 __attribute__((ext_vector_type(8)));
typedef float f32x4 __attribute__((ext_vector_type(4)));
typedef float f32x16 __attribute__((ext_vector_type(16)));
typedef unsigned int uint32x4 __attribute__((ext_vector_type(4)));

// ---------------------------------------------------------------------------
// Prep A: coords partial sums. 64 blocks x 256 threads, fully coalesced.
// partial[0..63] = sum x per block, partial[64..127] = sum y per block.
// ---------------------------------------------------------------------------
__global__ void prep_coords_kernel(const float* __restrict__ coords,
                                   float* __restrict__ partial) {
    __shared__ float red[512];
    int b = blockIdx.x, t = threadIdx.x;
    const f32x4* src = reinterpret_cast<const f32x4*>(coords + (size_t)b * 2048);
    f32x4 v0 = src[t * 2];
    f32x4 v1 = src[t * 2 + 1];
    red[t]       = v0[0] + v0[2] + v1[0] + v1[2];
    red[256 + t] = v0[1] + v0[3] + v1[1] + v1[3];
    __syncthreads();
    for (int s = 128; s > 0; s >>= 1) {
        if (t < s) { red[t] += red[t + s]; red[256 + t] += red[256 + t + s]; }
        __syncthreads();
    }
    if (t == 0) { partial[b] = red[0]; partial[64 + b] = red[256]; }
}

// ---------------------------------------------------------------------------
// Prep B: reduce partials -> mean -> 2-layer MLP -> spatial_emb[256]
// ---------------------------------------------------------------------------
__global__ void prep_emb_kernel(const float* __restrict__ partial,
                                const float* __restrict__ w1,
                                const float* __restrict__ b1,
                                const float* __restrict__ w2,
                                const float* __restrict__ b2,
                                float* __restrict__ emb) {
    __shared__ float red[128];
    __shared__ float h[DIM];
    int t = threadIdx.x; // 256
    if (t < 128) red[t] = partial[t];
    __syncthreads();
    for (int s = 32; s > 0; s >>= 1) {
        if (t < s) { red[t] += red[t + s]; red[64 + t] += red[64 + t + s]; }
        __syncthreads();
    }
    float mx = red[0] * (1.0f / NROWS);
    float my = red[64] * (1.0f / NROWS);
    float hv = mx * w1[2 * t] + my * w1[2 * t + 1] + b1[t];
    h[t] = hv > 0.f ? hv : 0.f;
    __syncthreads();
    float acc = b2[t];
    const float* wr = w2 + (size_t)t * DIM;
    #pragma unroll 4
    for (int k = 0; k < DIM; k += 4) {
        f32x4 wv = *reinterpret_cast<const f32x4*>(wr + k);
        acc += h[k] * wv[0] + h[k + 1] * wv[1] + h[k + 2] * wv[2] + h[k + 3] * wv[3];
    }
    emb[t] = acc;
}

// ---------------------------------------------------------------------------
// Prep C: memory f32 -> packed per-tile blob (KVB=32), pre-swizzled.
// Tile t (32768 B):
//   K part elems [0,8192): (kv 0..31, x 0..255) holds K[kt+kv][x ^ (kv<<3)]
//   V part elems [8192,16384): rows R 0..63 of 128 elems:
//       L = j ^ ((R&15)<<3); holds V^T[d=4R+(L>>5)][kv=L&31] = mem[kt+kv][d]
// ---------------------------------------------------------------------------
__global__ void prep_blob_kernel(const float* __restrict__ mem,
                                 __bf16* __restrict__ blob) {
    __shared__ __bf16 ltile[KVB][DIM]; // 16 KB
    int tile = blockIdx.x, t = threadIdx.x;
    int kt = tile * KVB;
    // coalesced load 32x256 f32 -> bf16 LDS
    for (int c = t; c < 1024; c += 256) {
        int e = c * 8, row = e >> 8, col = e & 255;
        const float* s = mem + (size_t)(kt + row) * DIM + col;
        f32x4 a = *reinterpret_cast<const f32x4*>(s);
        f32x4 b = *reinterpret_cast<const f32x4*>(s + 4);
        bf16x8 o;
        #pragma unroll
        for (int j = 0; j < 4; ++j) { o[j] = (__bf16)a[j]; o[j + 4] = (__bf16)b[j]; }
        *reinterpret_cast<bf16x8*>(&ltile[row][col]) = o;
    }
    __syncthreads();
    __bf16* kb = blob + (size_t)tile * 16384;
    __bf16* vb = kb + 8192;
    for (int c = t; c < 1024; c += 256) {
        int e = c * 8, kv = e >> 8, x0 = e & 255;
        bf16x8 o = *reinterpret_cast<const bf16x8*>(&ltile[kv][x0 ^ (kv << 3)]);
        *reinterpret_cast<bf16x8*>(kb + e) = o;
    }
    for (int c = t; c < 1024; c += 256) {
        int idx = c * 8, R = idx >> 7, j0 = idx & 127;
        int L0 = j0 ^ ((R & 15) << 3);
        int d = 4 * R + (L0 >> 5), kv0 = L0 & 31;
        bf16x8 o;
        #pragma unroll
        for (int j = 0; j < 8; ++j) o[j] = ltile[kv0 + j][d];
        *reinterpret_cast<bf16x8*>(vb + idx) = o;
    }
}

// ---------------------------------------------------------------------------
__device__ __forceinline__ void gload_lds16(const void* g, void* l) {
    __builtin_amdgcn_global_load_lds(
        (const __attribute__((address_space(1))) unsigned int*)g,
        (__attribute__((address_space(3))) unsigned int*)l,
        16, 0, 0);
}

__device__ __forceinline__ unsigned int pkbf(float a, float b) {
    union { __bf16 h; unsigned short u; } ua, ub;
    ua.h = (__bf16)a; ub.h = (__bf16)b;
    return (unsigned int)ua.u | ((unsigned int)ub.u << 16);
}

// ---------------------------------------------------------------------------
// Flash attention, lag-1 pipelined: per iter {QKT(t+1) | softmax(t) | PV(t)}.
// 512 thr = 8 waves x 32 q rows; KVB=32; 3 LDS buffers, stage leads by 2,
// counted vmcnt(4), raw s_barrier (no vmcnt(0) drain in main loop).
//
// 32x32x16 bf16 layouts (m74/m101):
//   A: row = lane&31, k = 8*(lane>>5)+i
//   B: col = lane&31, k = 8*(lane>>5)+i
//   C/D: col = lane&31, row = (reg&3) + 8*(reg>>2) + 4*(lane>>5)
// ---------------------------------------------------------------------------
__global__ __launch_bounds__(512, 2)
void flash_kernel(const float* __restrict__ feat,
                  const float* __restrict__ emb,
                  const __bf16* __restrict__ blob,
                  float* __restrict__ out) {
    __shared__ char smem[3 * TILE_B]; // 96 KB

    const int t = threadIdx.x;
    const int w = t >> 6;
    const int lane = t & 63;
    const int ln = lane & 31;
    const int hi = lane >> 5;

    const int qrow = blockIdx.x * 256 + w * 32 + ln;

    // ---- Q B-frags ----
    bf16x8 qf[16];
    {
        const float* frow = feat + (size_t)qrow * DIM;
        #pragma unroll
        for (int kd = 0; kd < 16; ++kd) {
            int d0 = kd * 16 + hi * 8;
            f32x4 a = *reinterpret_cast<const f32x4*>(frow + d0);
            f32x4 b = *reinterpret_cast<const f32x4*>(frow + d0 + 4);
            f32x4 ea = *reinterpret_cast<const f32x4*>(emb + d0);
            f32x4 eb = *reinterpret_cast<const f32x4*>(emb + d0 + 4);
            bf16x8 q;
            #pragma unroll
            for (int i = 0; i < 4; ++i) {
                q[i]     = (__bf16)((a[i] + ea[i]) * 0.0625f);
                q[i + 4] = (__bf16)((b[i] + eb[i]) * 0.0625f);
            }
            qf[kd] = q;
        }
    }

    f32x16 o[8];
    #pragma unroll
    for (int dt = 0; dt < 8; ++dt) o[dt] = (f32x16)(0.f);
    float m = -1e30f, l = 0.f;

    // staging addresses: per-wave 4 KB slice of each 32 KB tile
    const char* gsl = (const char*)blob + w * 1024 + lane * 16;
    char* bA = smem;               // tile t
    char* bB = smem + TILE_B;      // tile t+1
    char* bC = smem + 2 * TILE_B;  // staging target t+2

    #define STAGE(k, buf)                                            \
        {   const char* _g = gsl + (size_t)(k) * TILE_B;             \
            char* _d = (buf) + w * 1024;                             \
            _Pragma("unroll")                                        \
            for (int _j = 0; _j < 4; ++_j)                           \
                gload_lds16(_g + _j * 8192, _d + _j * 8192);         \
        }

    #define QKT(buf, dst)                                                        \
        {   f32x16 _acc = (f32x16)(0.f);                                         \
            const char* _kb = (buf) + ln * 512;                                  \
            __builtin_amdgcn_s_setprio(1);                                       \
            _Pragma("unroll")                                                    \
            for (int _kd = 0; _kd < 16; ++_kd) {                                 \
                const bf16x8 _a = *reinterpret_cast<const bf16x8*>(              \
                    _kb + (((_kd * 16 + hi * 8) ^ (ln * 8)) << 1));              \
                _acc = __builtin_amdgcn_mfma_f32_32x32x16_bf16(_a, qf[_kd], _acc, 0, 0, 0); \
            }                                                                    \
            __builtin_amdgcn_s_setprio(0);                                       \
            (dst) = _acc;                                                        \
        }

    // prologue
    STAGE(0, bA);
    STAGE(1, bB);
    asm volatile("s_waitcnt vmcnt(4)" ::: "memory");
    __builtin_amdgcn_s_barrier();
    asm volatile("" ::: "memory");
    f32x16 s_cur, s_nxt;
    QKT(bA, s_cur);

    #pragma unroll 1
    for (int kt = 0; kt < NT; ++kt) {
        if (kt + 2 < NT) STAGE(kt + 2, bC);
        if (kt + 1 < NT) {
            if (kt + 2 < NT) {
                asm volatile("s_waitcnt vmcnt(4)" ::: "memory");
            } else {
                asm volatile("s_waitcnt vmcnt(0)" ::: "memory");
            }
            __builtin_amdgcn_s_barrier();
            asm volatile("" ::: "memory");
            QKT(bB, s_nxt);
        }

        // ---- softmax(kt) on s_cur (q = ln; combine hi halves) ----
        float pmax = -1e30f;
        #pragma unroll
        for (int e = 0; e < 16; ++e) pmax = fmaxf(pmax, s_cur[e]);
        pmax = fmaxf(pmax, __shfl_xor(pmax, 32));
        if (pmax > m + 8.f) {   // defer-max (T13)
            float sc = __expf(m - pmax);
            m = pmax;
            l *= sc;
            #pragma unroll
            for (int dt = 0; dt < 8; ++dt) o[dt] = o[dt] * sc;
        }
        f32x16 p;
        float ladd = 0.f;
        #pragma unroll
        for (int e = 0; e < 16; ++e) {
            float pe = __expf(s_cur[e] - m);
            p[e] = pe;
            ladd += pe;
        }
        ladd += __shfl_xor(ladd, 32);
        l += ladd;

        // ---- PV(kt): O^T += mfma(V^T, P^T), 2 k-steps of 16 kv ----
        #pragma unroll
        for (int ks = 0; ks < 2; ++ks) {
            unsigned w01 = pkbf(p[ks * 8 + 0], p[ks * 8 + 1]);
            unsigned w23 = pkbf(p[ks * 8 + 2], p[ks * 8 + 3]);
            unsigned w45 = pkbf(p[ks * 8 + 4], p[ks * 8 + 5]);
            unsigned w67 = pkbf(p[ks * 8 + 6], p[ks * 8 + 7]);
            unsigned sA = hi ? w01 : w45;
            unsigned sB = hi ? w23 : w67;
            unsigned oA = hi ? w45 : w01;
            unsigned oB = hi ? w67 : w23;
            unsigned rA = __shfl_xor(sA, 32);
            unsigned rB = __shfl_xor(sB, 32);
            uint32x4 fw;
            fw[0] = hi ? rA : oA;
            fw[1] = hi ? rB : oB;
            fw[2] = hi ? oA : rA;
            fw[3] = hi ? oB : rB;
            bf16x8 pb = __builtin_bit_cast(bf16x8, fw);
            const int kv0 = ks * 16 + hi * 8;
            __builtin_amdgcn_s_setprio(1);
            #pragma unroll
            for (int dt = 0; dt < 8; ++dt) {
                int R = dt * 8 + (ln >> 2);
                int j = (((ln & 3) * 32 + kv0) ^ ((R & 15) << 3));
                const bf16x8 va = *reinterpret_cast<const bf16x8*>(
                    bA + 16384 + R * 256 + 2 * j);
                o[dt] = __builtin_amdgcn_mfma_f32_32x32x16_bf16(va, pb, o[dt], 0, 0, 0);
            }
            __builtin_amdgcn_s_setprio(0);
        }

        asm volatile("s_waitcnt lgkmcnt(0)" ::: "memory");
        __builtin_amdgcn_s_barrier();
        asm volatile("" ::: "memory");

        // rotate buffers, advance score pipeline
        char* tmp = bA; bA = bB; bB = bC; bC = tmp;
        s_cur = s_nxt;
    }

    // ---- epilogue: coalesced stores via LDS, 4 phases of 2 waves ----
    float linv = 1.f / l;
    const char* outb = (const char*)out;
    #pragma unroll 1
    for (int ph = 0; ph < 4; ++ph) {
        if ((w >> 1) == ph) {
            char* base = smem + (w & 1) * 32768 + ln * 1024;
            const int sw = (ln & 7) << 4;
            #pragma unroll
            for (int dt = 0; dt < 8; ++dt) {
                #pragma unroll
                for (int g = 0; g < 4; ++g) {
                    f32x4 v;
                    v[0] = o[dt][4 * g + 0] * linv;
                    v[1] = o[dt][4 * g + 1] * linv;
                    v[2] = o[dt][4 * g + 2] * linv;
                    v[3] = o[dt][4 * g + 3] * linv;
                    *reinterpret_cast<f32x4*>(base + ((dt * 128 + g * 32 + hi * 16) ^ sw)) = v;
                }
            }
        }
        __syncthreads();
        {
            char* gdst = (char*)out + ((size_t)blockIdx.x * 256 + ph * 64) * 1024;
            #pragma unroll
            for (int i = 0; i < 8; ++i) {
                int bo = t * 16 + i * 8192;
                int r = bo >> 10, off = bo & 1023;
                f32x4 v = *reinterpret_cast<const f32x4*>(
                    smem + r * 1024 + (off ^ ((r & 7) << 4)));
                *reinterpret_cast<f32x4*>(gdst + (size_t)r * 1024 + off) = v;
            }
        }
        __syncthreads();
    }
    #undef STAGE
    #undef QKT
}

// ---------------------------------------------------------------------------
extern "C" void kernel_launch(void* const* d_in, const int* in_sizes, int n_in,
                              void* d_out, int out_size, void* d_ws, size_t ws_size,
                              hipStream_t stream) {
    const float* features = (const float*)d_in[0];
    const float* coords   = (const float*)d_in[1];
    const float* memory   = (const float*)d_in[2];
    const float* w1       = (const float*)d_in[3];
    const float* b1       = (const float*)d_in[4];
    const float* w2       = (const float*)d_in[5];
    const float* b2       = (const float*)d_in[6];
    float* out = (float*)d_out;

    // ws: partial[128]f @0 | emb[256]f @512B | blob 2MiB @2048B
    float*  partial = (float*)d_ws;
    float*  emb     = (float*)((char*)d_ws + 512);
    __bf16* blob    = (__bf16*)((char*)d_ws + 2048);

    prep_coords_kernel<<<64, 256, 0, stream>>>(coords, partial);
    prep_blob_kernel<<<NT, 256, 0, stream>>>(memory, blob);
    prep_emb_kernel<<<1, 256, 0, stream>>>(partial, w1, b1, w2, b2, emb);
    flash_kernel<<<NROWS / 256, 512, 0, stream>>>(features, emb, blob, out);
}

// Round 6
// 206.160 us; speedup vs baseline: 6.3547x; 1.1654x over previous
//
#include <hip/hip_runtime.h>
#include <hip/hip_bf16.h>

#define DIM 256
#define MEMN 2048
#define NROWS 65536
#define KVB 32
#define NT 64            // MEMN / KVB
#define TILE_B 32768     // bytes per blob tile (K 16KB + V 16KB)

typedef __bf16 bf16x8 __attribute__((ext_vector_type(8)));
typedef float f32x4 __attribute__((ext_vector_type(4)));
typedef float f32x16 __attribute__((ext_vector_type(16)));
typedef unsigned int uint32x4 __attribute__((ext_vector_type(4)));

// ---------------------------------------------------------------------------
// Prep A: coords partial sums. 64 blocks x 256 threads, fully coalesced.
// ---------------------------------------------------------------------------
__global__ void prep_coords_kernel(const float* __restrict__ coords,
                                   float* __restrict__ partial) {
    __shared__ float red[512];
    int b = blockIdx.x, t = threadIdx.x;
    const f32x4* src = reinterpret_cast<const f32x4*>(coords + (size_t)b * 2048);
    f32x4 v0 = src[t * 2];
    f32x4 v1 = src[t * 2 + 1];
    red[t]       = v0[0] + v0[2] + v1[0] + v1[2];
    red[256 + t] = v0[1] + v0[3] + v1[1] + v1[3];
    __syncthreads();
    for (int s = 128; s > 0; s >>= 1) {
        if (t < s) { red[t] += red[t + s]; red[256 + t] += red[256 + t + s]; }
        __syncthreads();
    }
    if (t == 0) { partial[b] = red[0]; partial[64 + b] = red[256]; }
}

// ---------------------------------------------------------------------------
// Prep B: reduce partials -> mean -> 2-layer MLP -> spatial_emb[256]
// ---------------------------------------------------------------------------
__global__ void prep_emb_kernel(const float* __restrict__ partial,
                                const float* __restrict__ w1,
                                const float* __restrict__ b1,
                                const float* __restrict__ w2,
                                const float* __restrict__ b2,
                                float* __restrict__ emb) {
    __shared__ float red[128];
    __shared__ float h[DIM];
    int t = threadIdx.x; // 256
    if (t < 128) red[t] = partial[t];
    __syncthreads();
    for (int s = 32; s > 0; s >>= 1) {
        if (t < s) { red[t] += red[t + s]; red[64 + t] += red[64 + t + s]; }
        __syncthreads();
    }
    float mx = red[0] * (1.0f / NROWS);
    float my = red[64] * (1.0f / NROWS);
    float hv = mx * w1[2 * t] + my * w1[2 * t + 1] + b1[t];
    h[t] = hv > 0.f ? hv : 0.f;
    __syncthreads();
    float acc = b2[t];
    const float* wr = w2 + (size_t)t * DIM;
    #pragma unroll 4
    for (int k = 0; k < DIM; k += 4) {
        f32x4 wv = *reinterpret_cast<const f32x4*>(wr + k);
        acc += h[k] * wv[0] + h[k + 1] * wv[1] + h[k + 2] * wv[2] + h[k + 3] * wv[3];
    }
    emb[t] = acc;
}

// ---------------------------------------------------------------------------
// Prep C: memory f32 -> packed per-tile blob (KVB=32), pre-swizzled.
// Tile t (32768 B):
//   K part elems [0,8192): (kv 0..31, x 0..255) holds K[kt+kv][x ^ (kv<<3)]
//   V part elems [8192,16384): rows R 0..63 of 128 elems:
//       L = j ^ ((R&15)<<3); holds V^T[d=4R+(L>>5)][kv=L&31] = mem[kt+kv][d]
// ---------------------------------------------------------------------------
__global__ void prep_blob_kernel(const float* __restrict__ mem,
                                 __bf16* __restrict__ blob) {
    __shared__ __bf16 ltile[KVB][DIM]; // 16 KB
    int tile = blockIdx.x, t = threadIdx.x;
    int kt = tile * KVB;
    for (int c = t; c < 1024; c += 256) {
        int e = c * 8, row = e >> 8, col = e & 255;
        const float* s = mem + (size_t)(kt + row) * DIM + col;
        f32x4 a = *reinterpret_cast<const f32x4*>(s);
        f32x4 b = *reinterpret_cast<const f32x4*>(s + 4);
        bf16x8 o;
        #pragma unroll
        for (int j = 0; j < 4; ++j) { o[j] = (__bf16)a[j]; o[j + 4] = (__bf16)b[j]; }
        *reinterpret_cast<bf16x8*>(&ltile[row][col]) = o;
    }
    __syncthreads();
    __bf16* kb = blob + (size_t)tile * 16384;
    __bf16* vb = kb + 8192;
    for (int c = t; c < 1024; c += 256) {
        int e = c * 8, kv = e >> 8, x0 = e & 255;
        bf16x8 o = *reinterpret_cast<const bf16x8*>(&ltile[kv][x0 ^ (kv << 3)]);
        *reinterpret_cast<bf16x8*>(kb + e) = o;
    }
    for (int c = t; c < 1024; c += 256) {
        int idx = c * 8, R = idx >> 7, j0 = idx & 127;
        int L0 = j0 ^ ((R & 15) << 3);
        int d = 4 * R + (L0 >> 5), kv0 = L0 & 31;
        bf16x8 o;
        #pragma unroll
        for (int j = 0; j < 8; ++j) o[j] = ltile[kv0 + j][d];
        *reinterpret_cast<bf16x8*>(vb + idx) = o;
    }
}

// ---------------------------------------------------------------------------
__device__ __forceinline__ void gload_lds16(const void* g, void* l) {
    __builtin_amdgcn_global_load_lds(
        (const __attribute__((address_space(1))) unsigned int*)g,
        (__attribute__((address_space(3))) unsigned int*)l,
        16, 0, 0);
}

__device__ __forceinline__ unsigned int pkbf(float a, float b) {
    union { __bf16 h; unsigned short u; } ua, ub;
    ua.h = (__bf16)a; ub.h = (__bf16)b;
    return (unsigned int)ua.u | ((unsigned int)ub.u << 16);
}

// ---------------------------------------------------------------------------
// Flash attention. 256 thr = 4 waves x 32 q rows = 128 q/block; grid = 512
// (2 blocks/CU, LDS 64 KB each -> cross-block latency overlap, m114).
// KVB=32, 2 LDS buffers, ONE barrier per iter:
//   STAGE(t+1->B) | softmax(t) | PV(t from A) | vmcnt(0)+barrier | QKT(t+1,B)
//
// 32x32x16 bf16 layouts (m74/m101):
//   A: row = lane&31, k = 8*(lane>>5)+i
//   B: col = lane&31, k = 8*(lane>>5)+i
//   C/D: col = lane&31, row = (reg&3) + 8*(reg>>2) + 4*(lane>>5)
// ---------------------------------------------------------------------------
__global__ __launch_bounds__(256, 2)
void flash_kernel(const float* __restrict__ feat,
                  const float* __restrict__ emb,
                  const __bf16* __restrict__ blob,
                  float* __restrict__ out) {
    __shared__ char smem[2 * TILE_B]; // 64 KB

    const int t = threadIdx.x;
    const int w = t >> 6;
    const int lane = t & 63;
    const int ln = lane & 31;
    const int hi = lane >> 5;

    const int qrow = blockIdx.x * 128 + w * 32 + ln;

    // ---- Q B-frags ----
    bf16x8 qf[16];
    {
        const float* frow = feat + (size_t)qrow * DIM;
        #pragma unroll
        for (int kd = 0; kd < 16; ++kd) {
            int d0 = kd * 16 + hi * 8;
            f32x4 a = *reinterpret_cast<const f32x4*>(frow + d0);
            f32x4 b = *reinterpret_cast<const f32x4*>(frow + d0 + 4);
            f32x4 ea = *reinterpret_cast<const f32x4*>(emb + d0);
            f32x4 eb = *reinterpret_cast<const f32x4*>(emb + d0 + 4);
            bf16x8 q;
            #pragma unroll
            for (int i = 0; i < 4; ++i) {
                q[i]     = (__bf16)((a[i] + ea[i]) * 0.0625f);
                q[i + 4] = (__bf16)((b[i] + eb[i]) * 0.0625f);
            }
            qf[kd] = q;
        }
    }

    f32x16 o[8];
    #pragma unroll
    for (int dt = 0; dt < 8; ++dt) o[dt] = (f32x16)(0.f);
    float m = -1e30f, l = 0.f;

    // staging: per-wave 8 KB slice of each 32 KB tile
    const char* gsl = (const char*)blob + w * 8192 + lane * 16;
    char* bA = smem;
    char* bB = smem + TILE_B;

    #define STAGE(k, buf)                                            \
        {   const char* _g = gsl + (size_t)(k) * TILE_B;             \
            char* _d = (buf) + w * 8192;                             \
            _Pragma("unroll")                                        \
            for (int _j = 0; _j < 8; ++_j)                           \
                gload_lds16(_g + _j * 1024, _d + _j * 1024);         \
        }

    #define QKT(buf, dst)                                                        \
        {   f32x16 _acc = (f32x16)(0.f);                                         \
            const char* _kb = (buf) + ln * 512;                                  \
            __builtin_amdgcn_s_setprio(1);                                       \
            _Pragma("unroll")                                                    \
            for (int _kd = 0; _kd < 16; ++_kd) {                                 \
                const bf16x8 _a = *reinterpret_cast<const bf16x8*>(              \
                    _kb + (((_kd * 16 + hi * 8) ^ (ln * 8)) << 1));              \
                _acc = __builtin_amdgcn_mfma_f32_32x32x16_bf16(_a, qf[_kd], _acc, 0, 0, 0); \
            }                                                                    \
            __builtin_amdgcn_s_setprio(0);                                       \
            (dst) = _acc;                                                        \
        }

    // prologue: stage + compute scores for tile 0
    STAGE(0, bA);
    asm volatile("s_waitcnt vmcnt(0)" ::: "memory");
    __builtin_amdgcn_s_barrier();
    asm volatile("" ::: "memory");
    f32x16 s_cur, s_nxt;
    QKT(bA, s_cur);

    #pragma unroll 1
    for (int kt = 0; kt < NT; ++kt) {
        if (kt + 1 < NT) STAGE(kt + 1, bB);

        // ---- softmax(kt) on s_cur (q = ln; combine hi halves) ----
        float pmax = -1e30f;
        #pragma unroll
        for (int e = 0; e < 16; ++e) pmax = fmaxf(pmax, s_cur[e]);
        pmax = fmaxf(pmax, __shfl_xor(pmax, 32));
        if (pmax > m + 8.f) {   // defer-max (T13)
            float sc = __expf(m - pmax);
            m = pmax;
            l *= sc;
            #pragma unroll
            for (int dt = 0; dt < 8; ++dt) o[dt] = o[dt] * sc;
        }
        f32x16 p;
        float ladd = 0.f;
        #pragma unroll
        for (int e = 0; e < 16; ++e) {
            float pe = __expf(s_cur[e] - m);
            p[e] = pe;
            ladd += pe;
        }
        ladd += __shfl_xor(ladd, 32);
        l += ladd;

        // ---- PV(kt): O^T += mfma(V^T, P^T), 2 k-steps of 16 kv ----
        #pragma unroll
        for (int ks = 0; ks < 2; ++ks) {
            unsigned w01 = pkbf(p[ks * 8 + 0], p[ks * 8 + 1]);
            unsigned w23 = pkbf(p[ks * 8 + 2], p[ks * 8 + 3]);
            unsigned w45 = pkbf(p[ks * 8 + 4], p[ks * 8 + 5]);
            unsigned w67 = pkbf(p[ks * 8 + 6], p[ks * 8 + 7]);
            unsigned sA = hi ? w01 : w45;
            unsigned sB = hi ? w23 : w67;
            unsigned oA = hi ? w45 : w01;
            unsigned oB = hi ? w67 : w23;
            unsigned rA = __shfl_xor(sA, 32);
            unsigned rB = __shfl_xor(sB, 32);
            uint32x4 fw;
            fw[0] = hi ? rA : oA;
            fw[1] = hi ? rB : oB;
            fw[2] = hi ? oA : rA;
            fw[3] = hi ? oB : rB;
            bf16x8 pb = __builtin_bit_cast(bf16x8, fw);
            const int kv0 = ks * 16 + hi * 8;
            __builtin_amdgcn_s_setprio(1);
            #pragma unroll
            for (int dt = 0; dt < 8; ++dt) {
                int R = dt * 8 + (ln >> 2);
                int j = (((ln & 3) * 32 + kv0) ^ ((R & 15) << 3));
                const bf16x8 va = *reinterpret_cast<const bf16x8*>(
                    bA + 16384 + R * 256 + 2 * j);
                o[dt] = __builtin_amdgcn_mfma_f32_32x32x16_bf16(va, pb, o[dt], 0, 0, 0);
            }
            __builtin_amdgcn_s_setprio(0);
        }

        if (kt + 1 < NT) {
            // publish bB (stage drained under softmax+PV) and retire bA reads
            asm volatile("s_waitcnt vmcnt(0)" ::: "memory");
            __builtin_amdgcn_s_barrier();
            asm volatile("" ::: "memory");
            QKT(bB, s_nxt);
            char* tmp = bA; bA = bB; bB = tmp;
            s_cur = s_nxt;
        }
    }

    // ---- epilogue: coalesced stores via LDS, 2 phases of 2 waves ----
    float linv = 1.f / l;
    __syncthreads();
    #pragma unroll 1
    for (int ph = 0; ph < 2; ++ph) {
        if ((w >> 1) == ph) {
            char* base = smem + ((w & 1) * 32 + ln) * 1024;
            const int sw = (ln & 7) << 4;
            #pragma unroll
            for (int dt = 0; dt < 8; ++dt) {
                #pragma unroll
                for (int g = 0; g < 4; ++g) {
                    f32x4 v;
                    v[0] = o[dt][4 * g + 0] * linv;
                    v[1] = o[dt][4 * g + 1] * linv;
                    v[2] = o[dt][4 * g + 2] * linv;
                    v[3] = o[dt][4 * g + 3] * linv;
                    *reinterpret_cast<f32x4*>(base + ((dt * 128 + g * 32 + hi * 16) ^ sw)) = v;
                }
            }
        }
        __syncthreads();
        {
            char* gdst = (char*)out + ((size_t)blockIdx.x * 128 + ph * 64) * 1024;
            #pragma unroll
            for (int i = 0; i < 16; ++i) {
                int bo = t * 16 + i * 4096;
                int r = bo >> 10, off = bo & 1023;
                f32x4 v = *reinterpret_cast<const f32x4*>(
                    smem + r * 1024 + (off ^ ((r & 7) << 4)));
                *reinterpret_cast<f32x4*>(gdst + (size_t)r * 1024 + off) = v;
            }
        }
        __syncthreads();
    }
    #undef STAGE
    #undef QKT
}

// ---------------------------------------------------------------------------
extern "C" void kernel_launch(void* const* d_in, const int* in_sizes, int n_in,
                              void* d_out, int out_size, void* d_ws, size_t ws_size,
                              hipStream_t stream) {
    const float* features = (const float*)d_in[0];
    const float* coords   = (const float*)d_in[1];
    const float* memory   = (const float*)d_in[2];
    const float* w1       = (const float*)d_in[3];
    const float* b1       = (const float*)d_in[4];
    const float* w2       = (const float*)d_in[5];
    const float* b2       = (const float*)d_in[6];
    float* out = (float*)d_out;

    // ws: partial[128]f @0 | emb[256]f @512B | blob 2MiB @2048B
    float*  partial = (float*)d_ws;
    float*  emb     = (float*)((char*)d_ws + 512);
    __bf16* blob    = (__bf16*)((char*)d_ws + 2048);

    prep_coords_kernel<<<64, 256, 0, stream>>>(coords, partial);
    prep_blob_kernel<<<NT, 256, 0, stream>>>(memory, blob);
    prep_emb_kernel<<<1, 256, 0, stream>>>(partial, w1, b1, w2, b2, emb);
    flash_kernel<<<NROWS / 128, 256, 0, stream>>>(features, emb, blob, out);
}

// Round 7
// 192.286 us; speedup vs baseline: 6.8133x; 1.0722x over previous
//
#include <hip/hip_runtime.h>
#include <hip/hip_bf16.h>

#define DIM 256
#define MEMN 2048
#define NROWS 65536
#define KVB 32
#define NT 64            // MEMN / KVB
#define TILE_B 32768     // bytes per blob tile (K 16KB + V 16KB)

typedef __bf16 bf16x8 __attribute__((ext_vector_type(8)));
typedef float f32x4 __attribute__((ext_vector_type(4)));
typedef float f32x16 __attribute__((ext_vector_type(16)));
typedef unsigned int uint32x4 __attribute__((ext_vector_type(4)));

// ---------------------------------------------------------------------------
// Prep A: coords partial sums. 64 blocks x 256 threads, fully coalesced.
// ---------------------------------------------------------------------------
__global__ void prep_coords_kernel(const float* __restrict__ coords,
                                   float* __restrict__ partial) {
    __shared__ float red[512];
    int b = blockIdx.x, t = threadIdx.x;
    const f32x4* src = reinterpret_cast<const f32x4*>(coords + (size_t)b * 2048);
    f32x4 v0 = src[t * 2];
    f32x4 v1 = src[t * 2 + 1];
    red[t]       = v0[0] + v0[2] + v1[0] + v1[2];
    red[256 + t] = v0[1] + v0[3] + v1[1] + v1[3];
    __syncthreads();
    for (int s = 128; s > 0; s >>= 1) {
        if (t < s) { red[t] += red[t + s]; red[256 + t] += red[256 + t + s]; }
        __syncthreads();
    }
    if (t == 0) { partial[b] = red[0]; partial[64 + b] = red[256]; }
}

// ---------------------------------------------------------------------------
// Prep B: reduce partials -> mean -> 2-layer MLP -> spatial_emb[256]
// ---------------------------------------------------------------------------
__global__ void prep_emb_kernel(const float* __restrict__ partial,
                                const float* __restrict__ w1,
                                const float* __restrict__ b1,
                                const float* __restrict__ w2,
                                const float* __restrict__ b2,
                                float* __restrict__ emb) {
    __shared__ float red[128];
    __shared__ float h[DIM];
    int t = threadIdx.x; // 256
    if (t < 128) red[t] = partial[t];
    __syncthreads();
    for (int s = 32; s > 0; s >>= 1) {
        if (t < s) { red[t] += red[t + s]; red[64 + t] += red[64 + t + s]; }
        __syncthreads();
    }
    float mx = red[0] * (1.0f / NROWS);
    float my = red[64] * (1.0f / NROWS);
    float hv = mx * w1[2 * t] + my * w1[2 * t + 1] + b1[t];
    h[t] = hv > 0.f ? hv : 0.f;
    __syncthreads();
    float acc = b2[t];
    const float* wr = w2 + (size_t)t * DIM;
    #pragma unroll 4
    for (int k = 0; k < DIM; k += 4) {
        f32x4 wv = *reinterpret_cast<const f32x4*>(wr + k);
        acc += h[k] * wv[0] + h[k + 1] * wv[1] + h[k + 2] * wv[2] + h[k + 3] * wv[3];
    }
    emb[t] = acc;
}

// ---------------------------------------------------------------------------
// Prep C: memory f32 -> packed per-tile blob (KVB=32), pre-swizzled.
// Tile t (32768 B):
//   K part elems [0,8192): (kv 0..31, x 0..255) holds K[kt+kv][x ^ (kv<<3)]
//   V part elems [8192,16384): rows R 0..63 of 128 elems:
//       L = j ^ ((R&15)<<3); holds V^T[d=4R+(L>>5)][kv=L&31] = mem[kt+kv][d]
// ---------------------------------------------------------------------------
__global__ void prep_blob_kernel(const float* __restrict__ mem,
                                 __bf16* __restrict__ blob) {
    __shared__ __bf16 ltile[KVB][DIM]; // 16 KB
    int tile = blockIdx.x, t = threadIdx.x;
    int kt = tile * KVB;
    for (int c = t; c < 1024; c += 256) {
        int e = c * 8, row = e >> 8, col = e & 255;
        const float* s = mem + (size_t)(kt + row) * DIM + col;
        f32x4 a = *reinterpret_cast<const f32x4*>(s);
        f32x4 b = *reinterpret_cast<const f32x4*>(s + 4);
        bf16x8 o;
        #pragma unroll
        for (int j = 0; j < 4; ++j) { o[j] = (__bf16)a[j]; o[j + 4] = (__bf16)b[j]; }
        *reinterpret_cast<bf16x8*>(&ltile[row][col]) = o;
    }
    __syncthreads();
    __bf16* kb = blob + (size_t)tile * 16384;
    __bf16* vb = kb + 8192;
    for (int c = t; c < 1024; c += 256) {
        int e = c * 8, kv = e >> 8, x0 = e & 255;
        bf16x8 o = *reinterpret_cast<const bf16x8*>(&ltile[kv][x0 ^ (kv << 3)]);
        *reinterpret_cast<bf16x8*>(kb + e) = o;
    }
    for (int c = t; c < 1024; c += 256) {
        int idx = c * 8, R = idx >> 7, j0 = idx & 127;
        int L0 = j0 ^ ((R & 15) << 3);
        int d = 4 * R + (L0 >> 5), kv0 = L0 & 31;
        bf16x8 o;
        #pragma unroll
        for (int j = 0; j < 8; ++j) o[j] = ltile[kv0 + j][d];
        *reinterpret_cast<bf16x8*>(vb + idx) = o;
    }
}

// ---------------------------------------------------------------------------
__device__ __forceinline__ void gload_lds16(const void* g, void* l) {
    __builtin_amdgcn_global_load_lds(
        (const __attribute__((address_space(1))) unsigned int*)g,
        (__attribute__((address_space(3))) unsigned int*)l,
        16, 0, 0);
}

__device__ __forceinline__ unsigned int pkbf(float a, float b) {
    union { __bf16 h; unsigned short u; } ua, ub;
    ua.h = (__bf16)a; ub.h = (__bf16)b;
    return (unsigned int)ua.u | ((unsigned int)ub.u << 16);
}

__device__ __forceinline__ float fexp2(float x) {
#if __has_builtin(__builtin_amdgcn_exp2f)
    return __builtin_amdgcn_exp2f(x);
#else
    return exp2f(x);
#endif
}

// ---------------------------------------------------------------------------
// Flash attention. 256 thr = 4 waves x 32 q rows = 128 q/block; grid = 512
// (2 blocks/CU, LDS 64 KB each). Softmax in exp2 domain (log2e folded into
// Q scale). Per-iter schedule (2 barriers):
//   [softmax(t) -> pb] ; vmcnt(0)+barrier1 ;
//   CLUSTER: PV(t, bA) interleaved with dual-acc QKT(t+1, bB) ;
//   barrier2 ; STAGE(t+2 -> bA) ; swap
//
// 32x32x16 bf16 layouts (m74/m101):
//   A: row = lane&31, k = 8*(lane>>5)+i
//   B: col = lane&31, k = 8*(lane>>5)+i
//   C/D: col = lane&31, row = (reg&3) + 8*(reg>>2) + 4*(lane>>5)
// ---------------------------------------------------------------------------
__global__ __launch_bounds__(256, 2)
void flash_kernel(const float* __restrict__ feat,
                  const float* __restrict__ emb,
                  const __bf16* __restrict__ blob,
                  float* __restrict__ out) {
    __shared__ char smem[2 * TILE_B]; // 64 KB

    const int t = threadIdx.x;
    const int w = t >> 6;
    const int lane = t & 63;
    const int ln = lane & 31;
    const int hi = lane >> 5;

    const int qrow = blockIdx.x * 128 + w * 32 + ln;

    // ---- Q B-frags, scaled by (1/16)*log2(e) for exp2-domain softmax ----
    const float QS = 0.0901684463f;
    bf16x8 qf[16];
    {
        const float* frow = feat + (size_t)qrow * DIM;
        #pragma unroll
        for (int kd = 0; kd < 16; ++kd) {
            int d0 = kd * 16 + hi * 8;
            f32x4 a = *reinterpret_cast<const f32x4*>(frow + d0);
            f32x4 b = *reinterpret_cast<const f32x4*>(frow + d0 + 4);
            f32x4 ea = *reinterpret_cast<const f32x4*>(emb + d0);
            f32x4 eb = *reinterpret_cast<const f32x4*>(emb + d0 + 4);
            bf16x8 q;
            #pragma unroll
            for (int i = 0; i < 4; ++i) {
                q[i]     = (__bf16)((a[i] + ea[i]) * QS);
                q[i + 4] = (__bf16)((b[i] + eb[i]) * QS);
            }
            qf[kd] = q;
        }
    }

    f32x16 o[8];
    #pragma unroll
    for (int dt = 0; dt < 8; ++dt) o[dt] = (f32x16)(0.f);
    float m = -1e30f, l = 0.f;

    const char* gsl = (const char*)blob + w * 8192 + lane * 16;
    char* bA = smem;
    char* bB = smem + TILE_B;

    f32x16 sa, sb;      // dual QKT accumulators
    bf16x8 pb0, pb1;    // packed P fragments for the two PV k-steps

    #define STAGE(k, buf)                                            \
        {   const char* _g = gsl + (size_t)(k) * TILE_B;             \
            char* _d = (buf) + w * 8192;                             \
            _Pragma("unroll")                                        \
            for (int _j = 0; _j < 8; ++_j)                           \
                gload_lds16(_g + _j * 1024, _d + _j * 1024);         \
        }

    #define KFRAG(buf, kd) \
        (*reinterpret_cast<const bf16x8*>((buf) + ln * 512 + ((((kd) * 16 + hi * 8) ^ (ln * 8)) << 1)))

    // V frag for output tile dt, k-step ks
    #define VFRAG(buf, dt, ks)                                                   \
        (*reinterpret_cast<const bf16x8*>((buf) + 16384 +                        \
            ((dt) * 8 + (ln >> 2)) * 256 +                                       \
            (((((ln & 3) * 32 + (ks) * 16 + hi * 8)) ^ ((((dt) * 8 + (ln >> 2)) & 15) << 3)) << 1)))

    // softmax(t): merge sa+sb, online-max (base-2), exp2, pack pb0/pb1
    #define SOFTMAX()                                                            \
        {   f32x16 _s;                                                           \
            _Pragma("unroll")                                                    \
            for (int _e = 0; _e < 16; ++_e) _s[_e] = sa[_e] + sb[_e];            \
            float _pm = fmaxf(_s[0], _s[1]);                                     \
            _Pragma("unroll")                                                    \
            for (int _e = 2; _e < 16; ++_e) _pm = fmaxf(_pm, _s[_e]);            \
            _pm = fmaxf(_pm, __shfl_xor(_pm, 32));                               \
            if (__any(_pm > m + 11.5f)) {                                        \
                float _mn = fmaxf(m, _pm);                                       \
                float _sc = fexp2(m - _mn);                                      \
                m = _mn;                                                         \
                l *= _sc;                                                        \
                _Pragma("unroll")                                                \
                for (int _dt = 0; _dt < 8; ++_dt) o[_dt] = o[_dt] * _sc;         \
            }                                                                    \
            float _la = 0.f;                                                     \
            _Pragma("unroll")                                                    \
            for (int _e = 0; _e < 16; ++_e) {                                    \
                float _p = fexp2(_s[_e] - m);                                    \
                _s[_e] = _p;                                                     \
                _la += _p;                                                       \
            }                                                                    \
            _la += __shfl_xor(_la, 32);                                          \
            l += _la;                                                            \
            _Pragma("unroll")                                                    \
            for (int _ks = 0; _ks < 2; ++_ks) {                                  \
                unsigned _w01 = pkbf(_s[_ks * 8 + 0], _s[_ks * 8 + 1]);          \
                unsigned _w23 = pkbf(_s[_ks * 8 + 2], _s[_ks * 8 + 3]);          \
                unsigned _w45 = pkbf(_s[_ks * 8 + 4], _s[_ks * 8 + 5]);          \
                unsigned _w67 = pkbf(_s[_ks * 8 + 6], _s[_ks * 8 + 7]);          \
                unsigned _sA = hi ? _w01 : _w45;                                 \
                unsigned _sB = hi ? _w23 : _w67;                                 \
                unsigned _oA = hi ? _w45 : _w01;                                 \
                unsigned _oB = hi ? _w67 : _w23;                                 \
                unsigned _rA = __shfl_xor(_sA, 32);                              \
                unsigned _rB = __shfl_xor(_sB, 32);                              \
                uint32x4 _fw;                                                    \
                _fw[0] = hi ? _rA : _oA;                                         \
                _fw[1] = hi ? _rB : _oB;                                         \
                _fw[2] = hi ? _oA : _rA;                                         \
                _fw[3] = hi ? _oB : _rB;                                         \
                if (_ks == 0) pb0 = __builtin_bit_cast(bf16x8, _fw);             \
                else          pb1 = __builtin_bit_cast(bf16x8, _fw);             \
            }                                                                    \
        }

    // ---- prologue ----
    STAGE(0, bA);
    asm volatile("s_waitcnt vmcnt(0)" ::: "memory");
    __builtin_amdgcn_s_barrier();
    asm volatile("" ::: "memory");
    // QKT(0) dual-acc from bA
    sa = (f32x16)(0.f);
    sb = (f32x16)(0.f);
    __builtin_amdgcn_s_setprio(1);
    #pragma unroll
    for (int i = 0; i < 8; ++i) {
        sa = __builtin_amdgcn_mfma_f32_32x32x16_bf16(KFRAG(bA, 2 * i),     qf[2 * i],     sa, 0, 0, 0);
        sb = __builtin_amdgcn_mfma_f32_32x32x16_bf16(KFRAG(bA, 2 * i + 1), qf[2 * i + 1], sb, 0, 0, 0);
    }
    __builtin_amdgcn_s_setprio(0);
    STAGE(1, bB);
    SOFTMAX();
    asm volatile("s_waitcnt vmcnt(0)" ::: "memory");
    __builtin_amdgcn_s_barrier();
    asm volatile("" ::: "memory");

    // ---- main loop ----
    #pragma unroll 1
    for (int kt = 0; kt < NT - 1; ++kt) {
        // CLUSTER: PV(kt, bA) || QKT(kt+1, bB), interleaved
        sa = (f32x16)(0.f);
        sb = (f32x16)(0.f);
        __builtin_amdgcn_s_setprio(1);
        #pragma unroll
        for (int i = 0; i < 8; ++i) {
            sa = __builtin_amdgcn_mfma_f32_32x32x16_bf16(KFRAG(bB, 2 * i),     qf[2 * i],     sa, 0, 0, 0);
            o[i] = __builtin_amdgcn_mfma_f32_32x32x16_bf16(VFRAG(bA, i, 0), pb0, o[i], 0, 0, 0);
            sb = __builtin_amdgcn_mfma_f32_32x32x16_bf16(KFRAG(bB, 2 * i + 1), qf[2 * i + 1], sb, 0, 0, 0);
            o[i] = __builtin_amdgcn_mfma_f32_32x32x16_bf16(VFRAG(bA, i, 1), pb1, o[i], 0, 0, 0);
        }
        __builtin_amdgcn_s_setprio(0);

        // barrier2: all waves done reading bA before restaging it
        asm volatile("" ::: "memory");
        __builtin_amdgcn_s_barrier();
        asm volatile("" ::: "memory");

        if (kt + 2 < NT) STAGE(kt + 2, bA);
        SOFTMAX();   // softmax(kt+1) -> pb0/pb1; stage drains underneath
        asm volatile("s_waitcnt vmcnt(0)" ::: "memory");
        __builtin_amdgcn_s_barrier();   // barrier1: publish restaged buffer
        asm volatile("" ::: "memory");

        char* tmp = bA; bA = bB; bB = tmp;
    }

    // ---- tail: PV(NT-1) from bA ----
    __builtin_amdgcn_s_setprio(1);
    #pragma unroll
    for (int i = 0; i < 8; ++i) {
        o[i] = __builtin_amdgcn_mfma_f32_32x32x16_bf16(VFRAG(bA, i, 0), pb0, o[i], 0, 0, 0);
        o[i] = __builtin_amdgcn_mfma_f32_32x32x16_bf16(VFRAG(bA, i, 1), pb1, o[i], 0, 0, 0);
    }
    __builtin_amdgcn_s_setprio(0);

    // ---- epilogue: coalesced stores via LDS, 2 phases of 2 waves ----
    float linv = 1.f / l;
    __syncthreads();
    #pragma unroll 1
    for (int ph = 0; ph < 2; ++ph) {
        if ((w >> 1) == ph) {
            char* base = smem + ((w & 1) * 32 + ln) * 1024;
            const int sw = (ln & 7) << 4;
            #pragma unroll
            for (int dt = 0; dt < 8; ++dt) {
                #pragma unroll
                for (int g = 0; g < 4; ++g) {
                    f32x4 v;
                    v[0] = o[dt][4 * g + 0] * linv;
                    v[1] = o[dt][4 * g + 1] * linv;
                    v[2] = o[dt][4 * g + 2] * linv;
                    v[3] = o[dt][4 * g + 3] * linv;
                    *reinterpret_cast<f32x4*>(base + ((dt * 128 + g * 32 + hi * 16) ^ sw)) = v;
                }
            }
        }
        __syncthreads();
        {
            char* gdst = (char*)out + ((size_t)blockIdx.x * 128 + ph * 64) * 1024;
            #pragma unroll
            for (int i = 0; i < 16; ++i) {
                int bo = t * 16 + i * 4096;
                int r = bo >> 10, off = bo & 1023;
                f32x4 v = *reinterpret_cast<const f32x4*>(
                    smem + r * 1024 + (off ^ ((r & 7) << 4)));
                *reinterpret_cast<f32x4*>(gdst + (size_t)r * 1024 + off) = v;
            }
        }
        __syncthreads();
    }
    #undef STAGE
    #undef KFRAG
    #undef VFRAG
    #undef SOFTMAX
}

// ---------------------------------------------------------------------------
extern "C" void kernel_launch(void* const* d_in, const int* in_sizes, int n_in,
                              void* d_out, int out_size, void* d_ws, size_t ws_size,
                              hipStream_t stream) {
    const float* features = (const float*)d_in[0];
    const float* coords   = (const float*)d_in[1];
    const float* memory   = (const float*)d_in[2];
    const float* w1       = (const float*)d_in[3];
    const float* b1       = (const float*)d_in[4];
    const float* w2       = (const float*)d_in[5];
    const float* b2       = (const float*)d_in[6];
    float* out = (float*)d_out;

    // ws: partial[128]f @0 | emb[256]f @512B | blob 2MiB @2048B
    float*  partial = (float*)d_ws;
    float*  emb     = (float*)((char*)d_ws + 512);
    __bf16* blob    = (__bf16*)((char*)d_ws + 2048);

    prep_coords_kernel<<<64, 256, 0, stream>>>(coords, partial);
    prep_blob_kernel<<<NT, 256, 0, stream>>>(memory, blob);
    prep_emb_kernel<<<1, 256, 0, stream>>>(partial, w1, b1, w2, b2, emb);
    flash_kernel<<<NROWS / 128, 256, 0, stream>>>(features, emb, blob, out);
}